// Round 1
// baseline (657.060 us; speedup 1.0000x reference)
//
#include <hip/hip_runtime.h>
#include <math.h>

// Problem constants (fixed by the reference)
static constexpr int N    = 50000;   // nodes
static constexpr int E    = 800000;  // edges
static constexpr int TE   = E + N;   // edges + self loops
static constexpr int HD   = 64;      // hidden dim (= F)
static constexpr int NC   = 16;      // conv1d channels
static constexpr int TOT  = 193;     // concat dim

// ---------------- graph preprocessing ----------------

__global__ void k_init(int* __restrict__ deg, int* __restrict__ fill) {
    int i = blockIdx.x * blockDim.x + threadIdx.x;
    if (i < N) { deg[i] = 1; fill[i] = 0; }   // deg starts at 1 (self loop)
}

__global__ void k_count(const int* __restrict__ dst, int* __restrict__ deg) {
    int e = blockIdx.x * blockDim.x + threadIdx.x;
    if (e < E) atomicAdd(&deg[dst[e]], 1);
}

// single-block exclusive scan of deg -> row_ptr (N+1)
__global__ void k_scan(const int* __restrict__ deg, int* __restrict__ row_ptr) {
    __shared__ int sums[1024];
    const int t = threadIdx.x;
    const int CH = (N + 1023) / 1024;  // 49
    int lo = t * CH;
    int hi = lo + CH; if (hi > N) hi = N;
    int s = 0;
    for (int i = lo; i < hi; ++i) s += deg[i];
    sums[t] = s;
    __syncthreads();
    // Hillis-Steele inclusive scan
    for (int off = 1; off < 1024; off <<= 1) {
        int v = (t >= off) ? sums[t - off] : 0;
        __syncthreads();
        sums[t] += v;
        __syncthreads();
    }
    int base = sums[t] - s;  // exclusive prefix of this chunk
    for (int i = lo; i < hi; ++i) { row_ptr[i] = base; base += deg[i]; }
    if (t == 1023) row_ptr[N] = sums[1023];
}

__global__ void k_dinv(const int* __restrict__ deg, float* __restrict__ dinv) {
    int i = blockIdx.x * blockDim.x + threadIdx.x;
    if (i < N) dinv[i] = rsqrtf((float)deg[i]);
}

// scatter edges (+self loops) into CSR (by dst)
__global__ void k_fill(const int* __restrict__ src, const int* __restrict__ dst,
                       const int* __restrict__ row_ptr, int* __restrict__ fill,
                       const float* __restrict__ dinv,
                       int* __restrict__ col, float* __restrict__ wgt) {
    int idx = blockIdx.x * blockDim.x + threadIdx.x;
    if (idx < E) {
        int s = src[idx], d = dst[idx];
        int p = row_ptr[d] + atomicAdd(&fill[d], 1);
        col[p] = s;
        wgt[p] = dinv[s] * dinv[d];
    } else if (idx < TE) {
        int i = idx - E;
        int p = row_ptr[i] + atomicAdd(&fill[i], 1);
        col[p] = i;
        float dv = dinv[i];
        wgt[p] = dv * dv;
    }
}

// ---------------- dense compute ----------------

// T[n,:] = Ain[n,:] @ W   (64x64 weight, staged in LDS), 16 rows / block
__global__ __launch_bounds__(256) void k_gemm64(const float* __restrict__ Ain,
                                                const float* __restrict__ W,
                                                float* __restrict__ T) {
    __shared__ float Ws[64][64];
    __shared__ float Hs[16][64];
    const int tid = threadIdx.x;
    for (int i = tid; i < 64 * 64; i += 256) Ws[i >> 6][i & 63] = W[i];
    const int row0 = blockIdx.x * 16;
    for (int i = tid; i < 16 * 64; i += 256) {
        int r = i >> 6, c = i & 63;
        int gr = row0 + r;
        Hs[r][c] = (gr < N) ? Ain[gr * 64 + c] : 0.f;
    }
    __syncthreads();
    const int c = tid & 63;
    const int r0 = (tid >> 6) * 4;
    float a0 = 0.f, a1 = 0.f, a2 = 0.f, a3 = 0.f;
#pragma unroll
    for (int k = 0; k < 64; ++k) {
        float w = Ws[k][c];
        a0 += Hs[r0 + 0][k] * w;
        a1 += Hs[r0 + 1][k] * w;
        a2 += Hs[r0 + 2][k] * w;
        a3 += Hs[r0 + 3][k] * w;
    }
    if (row0 + r0 + 0 < N) T[(row0 + r0 + 0) * 64 + c] = a0;
    if (row0 + r0 + 1 < N) T[(row0 + r0 + 1) * 64 + c] = a1;
    if (row0 + r0 + 2 < N) T[(row0 + r0 + 2) * 64 + c] = a2;
    if (row0 + r0 + 3 < N) T[(row0 + r0 + 3) * 64 + c] = a3;
}

// A[n,f] = bias[f] + sum_p wgt[p] * T[col[p], f]   — one wave per node
__global__ __launch_bounds__(256) void k_agg(const float* __restrict__ T,
                                             const int* __restrict__ row_ptr,
                                             const int* __restrict__ col,
                                             const float* __restrict__ wgt,
                                             const float* __restrict__ bias,
                                             float* __restrict__ Aout) {
    int wave = (blockIdx.x * blockDim.x + threadIdx.x) >> 6;
    int lane = threadIdx.x & 63;
    if (wave >= N) return;
    int p0 = row_ptr[wave], p1 = row_ptr[wave + 1];
    float acc = 0.f;
    for (int p = p0; p < p1; ++p) {
        float w = wgt[p];
        int cc = col[p];
        acc += w * T[cc * 64 + lane];
    }
    Aout[wave * 64 + lane] = acc + bias[lane];
}

// out[n,c] (+)= sum_j A[n,j] * conv_w[c, LAYER*64 + j]  (+ conv_b on INIT)
template <int LAYER, bool INIT>
__global__ __launch_bounds__(256) void k_proj(const float* __restrict__ A,
                                              const float* __restrict__ conv_w,
                                              const float* __restrict__ conv_b,
                                              float* __restrict__ out) {
    int idx = blockIdx.x * blockDim.x + threadIdx.x;
    if (idx >= N * NC) return;
    int n = idx >> 4, c = idx & 15;
    const float* wrow = conv_w + c * TOT + LAYER * 64;
    const float* arow = A + n * 64;
    float acc = INIT ? conv_b[c] : out[idx];
#pragma unroll
    for (int j = 0; j < 64; ++j) acc += arow[j] * wrow[j];
    out[idx] = acc;
}

// t4[n] = dot(A[n,:], W3)  — one wave per node, butterfly reduce
__global__ __launch_bounds__(256) void k_gemv(const float* __restrict__ Ain,
                                              const float* __restrict__ W3,
                                              float* __restrict__ t4) {
    int wave = (blockIdx.x * blockDim.x + threadIdx.x) >> 6;
    int lane = threadIdx.x & 63;
    if (wave >= N) return;
    float v = Ain[wave * 64 + lane] * W3[lane];
#pragma unroll
    for (int off = 32; off; off >>= 1) v += __shfl_xor(v, off);
    if (lane == 0) t4[wave] = v;
}

// h4 = b3 + agg(t4); out[n,c] += h4 * conv_w[c,192]
__global__ void k_agg4_out(const float* __restrict__ t4,
                           const int* __restrict__ row_ptr,
                           const int* __restrict__ col,
                           const float* __restrict__ wgt,
                           const float* __restrict__ b3,
                           const float* __restrict__ conv_w,
                           float* __restrict__ out) {
    int n = blockIdx.x * blockDim.x + threadIdx.x;
    if (n >= N) return;
    int p0 = row_ptr[n], p1 = row_ptr[n + 1];
    float acc = 0.f;
    for (int p = p0; p < p1; ++p) acc += wgt[p] * t4[col[p]];
    float h4 = acc + b3[0];
#pragma unroll
    for (int c = 0; c < NC; ++c)
        out[n * NC + c] += h4 * conv_w[c * TOT + 192];
}

// ---------------- launch ----------------

extern "C" void kernel_launch(void* const* d_in, const int* in_sizes, int n_in,
                              void* d_out, int out_size, void* d_ws, size_t ws_size,
                              hipStream_t stream) {
    const float* x   = (const float*)d_in[0];
    const int*   ei  = (const int*)d_in[1];
    const int*   src = ei;
    const int*   dst = ei + E;
    const float* W0  = (const float*)d_in[3];
    const float* b0  = (const float*)d_in[4];
    const float* W1  = (const float*)d_in[5];
    const float* b1  = (const float*)d_in[6];
    const float* W2  = (const float*)d_in[7];
    const float* b2  = (const float*)d_in[8];
    const float* W3  = (const float*)d_in[9];
    const float* b3  = (const float*)d_in[10];
    const float* cw  = (const float*)d_in[11];
    const float* cb  = (const float*)d_in[12];
    float* out = (float*)d_out;

    char* p = (char*)d_ws;
    auto alloc = [&](size_t nbytes) {
        char* r = p;
        p += (nbytes + 255) & ~(size_t)255;
        return (void*)r;
    };
    int*   deg     = (int*)alloc((size_t)N * 4);
    int*   fill    = (int*)alloc((size_t)N * 4);
    int*   row_ptr = (int*)alloc((size_t)(N + 1) * 4);
    float* dinv    = (float*)alloc((size_t)N * 4);
    int*   col     = (int*)alloc((size_t)TE * 4);
    float* wgt     = (float*)alloc((size_t)TE * 4);
    float* T       = (float*)alloc((size_t)N * 64 * 4);
    float* A       = (float*)alloc((size_t)N * 64 * 4);
    float* t4      = (float*)alloc((size_t)N * 4);

    // graph preprocessing
    k_init <<<(N + 255) / 256, 256, 0, stream>>>(deg, fill);
    k_count<<<(E + 255) / 256, 256, 0, stream>>>(dst, deg);
    k_scan <<<1, 1024, 0, stream>>>(deg, row_ptr);
    k_dinv <<<(N + 255) / 256, 256, 0, stream>>>(deg, dinv);
    k_fill <<<(TE + 255) / 256, 256, 0, stream>>>(src, dst, row_ptr, fill, dinv, col, wgt);

    const int gemmGrid = (N + 15) / 16;
    const int aggGrid  = (N * 64 + 255) / 256;   // one wave / node
    const int projGrid = (N * NC + 255) / 256;

    // layer 1 (input x)
    k_gemm64<<<gemmGrid, 256, 0, stream>>>(x, W0, T);
    k_agg   <<<aggGrid, 256, 0, stream>>>(T, row_ptr, col, wgt, b0, A);
    k_proj<0, true> <<<projGrid, 256, 0, stream>>>(A, cw, cb, out);
    // layer 2
    k_gemm64<<<gemmGrid, 256, 0, stream>>>(A, W1, T);
    k_agg   <<<aggGrid, 256, 0, stream>>>(T, row_ptr, col, wgt, b1, A);
    k_proj<1, false><<<projGrid, 256, 0, stream>>>(A, cw, cb, out);
    // layer 3
    k_gemm64<<<gemmGrid, 256, 0, stream>>>(A, W2, T);
    k_agg   <<<aggGrid, 256, 0, stream>>>(T, row_ptr, col, wgt, b2, A);
    k_proj<2, false><<<projGrid, 256, 0, stream>>>(A, cw, cb, out);
    // layer 4 (H -> 1) + final column of projection
    k_gemv  <<<aggGrid, 256, 0, stream>>>(A, W3, t4);
    k_agg4_out<<<(N + 255) / 256, 256, 0, stream>>>(t4, row_ptr, col, wgt, b3, cw, out);
}

// Round 2
// 445.008 us; speedup vs baseline: 1.4765x; 1.4765x over previous
//
#include <hip/hip_runtime.h>
#include <math.h>

// Problem constants (fixed by the reference)
static constexpr int N    = 50000;   // nodes
static constexpr int E    = 800000;  // edges
static constexpr int TE   = E + N;   // edges + self loops
static constexpr int NC   = 16;      // conv1d channels
static constexpr int TOT  = 193;     // concat dim

// ---------------- graph preprocessing ----------------

__global__ void k_init(int* __restrict__ deg, int* __restrict__ fill,
                       int2* __restrict__ edges) {
    int i = blockIdx.x * blockDim.x + threadIdx.x;
    if (i < N) { deg[i] = 1; fill[i] = 0; }   // deg starts at 1 (self loop)
    if (i < 8) edges[TE + i] = make_int2(0, 0);  // pad for unrolled overrun
}

__global__ void k_count(const int* __restrict__ dst, int* __restrict__ deg) {
    int e = blockIdx.x * blockDim.x + threadIdx.x;
    if (e < E) atomicAdd(&deg[dst[e]], 1);
}

// single-block exclusive scan of deg -> row_ptr (N+1)
__global__ void k_scan(const int* __restrict__ deg, int* __restrict__ row_ptr) {
    __shared__ int sums[1024];
    const int t = threadIdx.x;
    const int CH = (N + 1023) / 1024;  // 49
    int lo = t * CH;
    int hi = lo + CH; if (hi > N) hi = N;
    int s = 0;
    for (int i = lo; i < hi; ++i) s += deg[i];
    sums[t] = s;
    __syncthreads();
    for (int off = 1; off < 1024; off <<= 1) {
        int v = (t >= off) ? sums[t - off] : 0;
        __syncthreads();
        sums[t] += v;
        __syncthreads();
    }
    int base = sums[t] - s;  // exclusive prefix of this chunk
    for (int i = lo; i < hi; ++i) { row_ptr[i] = base; base += deg[i]; }
    if (t == 1023) row_ptr[N] = sums[1023];
}

__global__ void k_dinv(const int* __restrict__ deg, float* __restrict__ dinv) {
    int i = blockIdx.x * blockDim.x + threadIdx.x;
    if (i < N) dinv[i] = rsqrtf((float)deg[i]);
}

// scatter edges (+self loops) into CSR (by dst), packed {col, wgt-bits}
__global__ void k_fill(const int* __restrict__ src, const int* __restrict__ dst,
                       const int* __restrict__ row_ptr, int* __restrict__ fill,
                       const float* __restrict__ dinv,
                       int2* __restrict__ edges) {
    int idx = blockIdx.x * blockDim.x + threadIdx.x;
    if (idx < E) {
        int s = src[idx], d = dst[idx];
        int p = row_ptr[d] + atomicAdd(&fill[d], 1);
        edges[p] = make_int2(s, __float_as_int(dinv[s] * dinv[d]));
    } else if (idx < TE) {
        int i = idx - E;
        int p = row_ptr[i] + atomicAdd(&fill[i], 1);
        float dv = dinv[i];
        edges[p] = make_int2(i, __float_as_int(dv * dv));
    }
}

// ---------------- dense compute ----------------

// T[n,:] = Ain[n,:] @ W   (64x64 weight, staged in LDS), 16 rows / block
__global__ __launch_bounds__(256) void k_gemm64(const float* __restrict__ Ain,
                                                const float* __restrict__ W,
                                                float* __restrict__ T) {
    __shared__ float Ws[64][64];
    __shared__ float Hs[16][64];
    const int tid = threadIdx.x;
    for (int i = tid; i < 64 * 64; i += 256) Ws[i >> 6][i & 63] = W[i];
    const int row0 = blockIdx.x * 16;
    for (int i = tid; i < 16 * 64; i += 256) {
        int r = i >> 6, c = i & 63;
        int gr = row0 + r;
        Hs[r][c] = (gr < N) ? Ain[gr * 64 + c] : 0.f;
    }
    __syncthreads();
    const int c = tid & 63;
    const int r0 = (tid >> 6) * 4;
    float a0 = 0.f, a1 = 0.f, a2 = 0.f, a3 = 0.f;
#pragma unroll
    for (int k = 0; k < 64; ++k) {
        float w = Ws[k][c];
        a0 += Hs[r0 + 0][k] * w;
        a1 += Hs[r0 + 1][k] * w;
        a2 += Hs[r0 + 2][k] * w;
        a3 += Hs[r0 + 3][k] * w;
    }
    if (row0 + r0 + 0 < N) T[(row0 + r0 + 0) * 64 + c] = a0;
    if (row0 + r0 + 1 < N) T[(row0 + r0 + 1) * 64 + c] = a1;
    if (row0 + r0 + 2 < N) T[(row0 + r0 + 2) * 64 + c] = a2;
    if (row0 + r0 + 3 < N) T[(row0 + r0 + 3) * 64 + c] = a3;
}

// Fused: A[n,:] = bias + sum_p wgt[p]*T[col[p],:]   (one wave / node, unroll 8)
//        + proj slice into out[n, 0:16]
//        + (layer 2) t4[n] = dot(A[n,:], W3)
template <int LAYER, bool WRITE_A, bool COMPUTE_T4>
__global__ __launch_bounds__(256) void k_agg_fused(
    const float* __restrict__ T,
    const int2* __restrict__ edges,
    const int* __restrict__ row_ptr,
    const float* __restrict__ bias,
    const float* __restrict__ conv_w,
    const float* __restrict__ conv_b,
    const float* __restrict__ W3,
    float* __restrict__ Aout,
    float* __restrict__ out,
    float* __restrict__ t4) {
    // conv_w slice [64][16], transposed + XOR-swizzled: element (j,c) at
    // (j<<4) + (c ^ ((j>>4)<<3))  -> 2-way banks on the read pattern (free)
    __shared__ float CWT[1024];
    const int tid = threadIdx.x;
    for (int idx = tid; idx < 1024; idx += 256) {
        int j = idx >> 4, c = idx & 15;
        CWT[(j << 4) + (c ^ ((j >> 4) << 3))] = conv_w[c * TOT + LAYER * 64 + j];
    }
    const int lane = tid & 63;
    const float bv = bias[lane];
    float w3v = 0.f;
    if constexpr (COMPUTE_T4) w3v = W3[lane];
    __syncthreads();

    const int n = (blockIdx.x * 256 + tid) >> 6;
    if (n >= N) return;

    const int p0 = __builtin_amdgcn_readfirstlane(row_ptr[n]);
    const int p1 = __builtin_amdgcn_readfirstlane(row_ptr[n + 1]);

    float acc0 = 0.f, acc1 = 0.f;
    for (int p = p0; p < p1; p += 8) {
        int2 e0 = edges[p + 0], e1 = edges[p + 1], e2 = edges[p + 2], e3 = edges[p + 3];
        int2 e4 = edges[p + 4], e5 = edges[p + 5], e6 = edges[p + 6], e7 = edges[p + 7];
        float t0 = T[e0.x * 64 + lane];
        float t1 = T[e1.x * 64 + lane];
        float t2 = T[e2.x * 64 + lane];
        float t3 = T[e3.x * 64 + lane];
        float t4r = T[e4.x * 64 + lane];
        float t5 = T[e5.x * 64 + lane];
        float t6 = T[e6.x * 64 + lane];
        float t7 = T[e7.x * 64 + lane];
        float w0 = __int_as_float(e0.y);
        float w1 = (p + 1 < p1) ? __int_as_float(e1.y) : 0.f;
        float w2 = (p + 2 < p1) ? __int_as_float(e2.y) : 0.f;
        float w3 = (p + 3 < p1) ? __int_as_float(e3.y) : 0.f;
        float w4 = (p + 4 < p1) ? __int_as_float(e4.y) : 0.f;
        float w5 = (p + 5 < p1) ? __int_as_float(e5.y) : 0.f;
        float w6 = (p + 6 < p1) ? __int_as_float(e6.y) : 0.f;
        float w7 = (p + 7 < p1) ? __int_as_float(e7.y) : 0.f;
        acc0 += w0 * t0; acc1 += w1 * t1;
        acc0 += w2 * t2; acc1 += w3 * t3;
        acc0 += w4 * t4r; acc1 += w5 * t5;
        acc0 += w6 * t6; acc1 += w7 * t7;
    }
    const float aval = acc0 + acc1 + bv;

    if constexpr (WRITE_A) Aout[n * 64 + lane] = aval;

    if constexpr (COMPUTE_T4) {
        float v = aval * w3v;
#pragma unroll
        for (int off = 32; off; off >>= 1) v += __shfl_xor(v, off);
        if (lane == 0) t4[n] = v;
    }

    // projection: lane = (c,g); partial dot over j = 16g..16g+15, reduce over g
    const int c = lane & 15, g = lane >> 4;
    float r = 0.f;
#pragma unroll
    for (int i = 0; i < 16; ++i) {
        int j = (g << 4) + i;
        float aj = __shfl(aval, j);
        r += aj * CWT[(j << 4) + (c ^ (g << 3))];
    }
    r += __shfl_xor(r, 16);
    r += __shfl_xor(r, 32);
    if (lane < 16) {
        int o = n * NC + c;
        out[o] = ((LAYER == 0) ? conv_b[c] : out[o]) + r;
    }
}

// h4 = b3 + agg(t4); out[n, :] += h4 * conv_w[:, 192]   (thread per node)
__global__ __launch_bounds__(256) void k_agg4_out(
    const float* __restrict__ t4, const int2* __restrict__ edges,
    const int* __restrict__ row_ptr, const float* __restrict__ b3,
    const float* __restrict__ conv_w, float* __restrict__ out) {
    int n = blockIdx.x * blockDim.x + threadIdx.x;
    if (n >= N) return;
    int p0 = row_ptr[n], p1 = row_ptr[n + 1];
    float a0 = 0.f, a1 = 0.f;
    for (int p = p0; p < p1; p += 4) {
        int2 e0 = edges[p + 0], e1 = edges[p + 1], e2 = edges[p + 2], e3 = edges[p + 3];
        float w0 = __int_as_float(e0.y);
        float w1 = (p + 1 < p1) ? __int_as_float(e1.y) : 0.f;
        float w2 = (p + 2 < p1) ? __int_as_float(e2.y) : 0.f;
        float w3 = (p + 3 < p1) ? __int_as_float(e3.y) : 0.f;
        a0 += w0 * t4[e0.x]; a1 += w1 * t4[e1.x];
        a0 += w2 * t4[e2.x]; a1 += w3 * t4[e3.x];
    }
    float h4 = a0 + a1 + b3[0];
    float4* o4 = (float4*)(out + n * NC);
#pragma unroll
    for (int k = 0; k < 4; ++k) {
        float4 v = o4[k];
        v.x += h4 * conv_w[(4 * k + 0) * TOT + 192];
        v.y += h4 * conv_w[(4 * k + 1) * TOT + 192];
        v.z += h4 * conv_w[(4 * k + 2) * TOT + 192];
        v.w += h4 * conv_w[(4 * k + 3) * TOT + 192];
        o4[k] = v;
    }
}

// ---------------- launch ----------------

extern "C" void kernel_launch(void* const* d_in, const int* in_sizes, int n_in,
                              void* d_out, int out_size, void* d_ws, size_t ws_size,
                              hipStream_t stream) {
    const float* x   = (const float*)d_in[0];
    const int*   ei  = (const int*)d_in[1];
    const int*   src = ei;
    const int*   dst = ei + E;
    const float* W0  = (const float*)d_in[3];
    const float* b0  = (const float*)d_in[4];
    const float* W1  = (const float*)d_in[5];
    const float* b1  = (const float*)d_in[6];
    const float* W2  = (const float*)d_in[7];
    const float* b2  = (const float*)d_in[8];
    const float* W3  = (const float*)d_in[9];
    const float* b3  = (const float*)d_in[10];
    const float* cw  = (const float*)d_in[11];
    const float* cb  = (const float*)d_in[12];
    float* out = (float*)d_out;

    char* p = (char*)d_ws;
    auto alloc = [&](size_t nbytes) {
        char* r = p;
        p += (nbytes + 255) & ~(size_t)255;
        return (void*)r;
    };
    int*   deg     = (int*)alloc((size_t)N * 4);
    int*   fill    = (int*)alloc((size_t)N * 4);
    int*   row_ptr = (int*)alloc((size_t)(N + 1) * 4);
    float* dinv    = (float*)alloc((size_t)N * 4);
    int2*  edges   = (int2*)alloc((size_t)(TE + 8) * 8);
    float* T       = (float*)alloc((size_t)N * 64 * 4);
    float* A       = (float*)alloc((size_t)N * 64 * 4);
    float* t4      = (float*)alloc((size_t)N * 4);

    // graph preprocessing
    k_init <<<(N + 255) / 256, 256, 0, stream>>>(deg, fill, edges);
    k_count<<<(E + 255) / 256, 256, 0, stream>>>(dst, deg);
    k_scan <<<1, 1024, 0, stream>>>(deg, row_ptr);
    k_dinv <<<(N + 255) / 256, 256, 0, stream>>>(deg, dinv);
    k_fill <<<(TE + 255) / 256, 256, 0, stream>>>(src, dst, row_ptr, fill, dinv, edges);

    const int gemmGrid = (N + 15) / 16;
    const int aggGrid  = (N + 3) / 4;   // one wave / node, 4 waves / block

    // layer 1 (input x)
    k_gemm64<<<gemmGrid, 256, 0, stream>>>(x, W0, T);
    k_agg_fused<0, true, false><<<aggGrid, 256, 0, stream>>>(
        T, edges, row_ptr, b0, cw, cb, nullptr, A, out, nullptr);
    // layer 2
    k_gemm64<<<gemmGrid, 256, 0, stream>>>(A, W1, T);
    k_agg_fused<1, true, false><<<aggGrid, 256, 0, stream>>>(
        T, edges, row_ptr, b1, cw, cb, nullptr, A, out, nullptr);
    // layer 3 (also computes t4 = A3 . W3; A3 itself not needed afterwards)
    k_gemm64<<<gemmGrid, 256, 0, stream>>>(A, W2, T);
    k_agg_fused<2, false, true><<<aggGrid, 256, 0, stream>>>(
        T, edges, row_ptr, b2, cw, cb, W3, nullptr, out, t4);
    // layer 4 (H -> 1) aggregation + final column of projection
    k_agg4_out<<<(N + 255) / 256, 256, 0, stream>>>(t4, edges, row_ptr, b3, cw, out);
}

// Round 3
// 376.475 us; speedup vs baseline: 1.7453x; 1.1820x over previous
//
#include <hip/hip_runtime.h>
#include <math.h>

// Problem constants (fixed by the reference)
static constexpr int N    = 50000;   // nodes
static constexpr int E    = 800000;  // edges
static constexpr int TE   = E + N;   // edges + self loops
static constexpr int NC   = 16;      // conv1d channels
static constexpr int TOT  = 193;     // concat dim
static constexpr int NB   = (N + 255) / 256;  // 196 scan blocks

// ---------------- graph preprocessing ----------------

__global__ void k_init(int* __restrict__ deg, int* __restrict__ fill,
                       int2* __restrict__ edges) {
    int i = blockIdx.x * blockDim.x + threadIdx.x;
    if (i < N) { deg[i] = 1; fill[i] = 0; }   // deg starts at 1 (self loop)
    if (i < 8) edges[TE + i] = make_int2(0, 0);  // pad for unrolled overrun
}

__global__ void k_count(const int* __restrict__ dst, int* __restrict__ deg) {
    int e = blockIdx.x * blockDim.x + threadIdx.x;
    if (e < E) atomicAdd(&deg[dst[e]], 1);
}

// hierarchical scan, stage 1: per-256-chunk sums
__global__ __launch_bounds__(256) void k_part(const int* __restrict__ deg,
                                              int* __restrict__ part) {
    __shared__ int red[256];
    const int t = threadIdx.x;
    int i = blockIdx.x * 256 + t;
    int v = (i < N) ? deg[i] : 0;
    red[t] = v;
    __syncthreads();
#pragma unroll
    for (int off = 128; off; off >>= 1) {
        if (t < off) red[t] += red[t + off];
        __syncthreads();
    }
    if (t == 0) part[blockIdx.x] = red[0];
}

// stage 2: exclusive scan of the 196 partials (single small block)
__global__ __launch_bounds__(256) void k_scanpart(int* __restrict__ part) {
    __shared__ int s[256];
    const int t = threadIdx.x;
    int v = (t < NB) ? part[t] : 0;
    s[t] = v;
    __syncthreads();
#pragma unroll
    for (int off = 1; off < 256; off <<= 1) {
        int u = (t >= off) ? s[t - off] : 0;
        __syncthreads();
        s[t] += u;
        __syncthreads();
    }
    if (t < NB) part[t] = s[t] - v;  // exclusive prefix
}

// stage 3: local inclusive scan + scatter row_ptr; fused dinv = rsqrt(deg)
__global__ __launch_bounds__(256) void k_scatter(const int* __restrict__ deg,
                                                 const int* __restrict__ part,
                                                 int* __restrict__ row_ptr,
                                                 float* __restrict__ dinv) {
    __shared__ int s[256];
    const int t = threadIdx.x;
    int i = blockIdx.x * 256 + t;
    int v = (i < N) ? deg[i] : 0;
    s[t] = v;
    __syncthreads();
#pragma unroll
    for (int off = 1; off < 256; off <<= 1) {
        int u = (t >= off) ? s[t - off] : 0;
        __syncthreads();
        s[t] += u;
        __syncthreads();
    }
    if (i < N) {
        int base = part[blockIdx.x];
        row_ptr[i] = base + s[t] - v;
        dinv[i] = rsqrtf((float)v);           // deg >= 1 always (self loop)
        if (i == N - 1) row_ptr[N] = base + s[t];
    }
}

// scatter edges (+self loops) into CSR (by dst), packed {col, wgt-bits}
__global__ void k_fill(const int* __restrict__ src, const int* __restrict__ dst,
                       const int* __restrict__ row_ptr, int* __restrict__ fill,
                       const float* __restrict__ dinv,
                       int2* __restrict__ edges) {
    int idx = blockIdx.x * blockDim.x + threadIdx.x;
    if (idx < E) {
        int s = src[idx], d = dst[idx];
        int p = row_ptr[d] + atomicAdd(&fill[d], 1);
        edges[p] = make_int2(s, __float_as_int(dinv[s] * dinv[d]));
    } else if (idx < TE) {
        int i = idx - E;
        int p = row_ptr[i] + atomicAdd(&fill[i], 1);
        float dv = dinv[i];
        edges[p] = make_int2(i, __float_as_int(dv * dv));
    }
}

// ---------------- dense compute ----------------

// T[n,:] = Ain[n,:] @ W   (64x64 weight, staged in LDS), 16 rows / block
__global__ __launch_bounds__(256) void k_gemm64(const float* __restrict__ Ain,
                                                const float* __restrict__ W,
                                                float* __restrict__ T) {
    __shared__ float Ws[64][64];
    __shared__ float Hs[16][64];
    const int tid = threadIdx.x;
    for (int i = tid; i < 64 * 64; i += 256) Ws[i >> 6][i & 63] = W[i];
    const int row0 = blockIdx.x * 16;
    for (int i = tid; i < 16 * 64; i += 256) {
        int r = i >> 6, c = i & 63;
        int gr = row0 + r;
        Hs[r][c] = (gr < N) ? Ain[gr * 64 + c] : 0.f;
    }
    __syncthreads();
    const int c = tid & 63;
    const int r0 = (tid >> 6) * 4;
    float a0 = 0.f, a1 = 0.f, a2 = 0.f, a3 = 0.f;
#pragma unroll
    for (int k = 0; k < 64; ++k) {
        float w = Ws[k][c];
        a0 += Hs[r0 + 0][k] * w;
        a1 += Hs[r0 + 1][k] * w;
        a2 += Hs[r0 + 2][k] * w;
        a3 += Hs[r0 + 3][k] * w;
    }
    if (row0 + r0 + 0 < N) T[(row0 + r0 + 0) * 64 + c] = a0;
    if (row0 + r0 + 1 < N) T[(row0 + r0 + 1) * 64 + c] = a1;
    if (row0 + r0 + 2 < N) T[(row0 + r0 + 2) * 64 + c] = a2;
    if (row0 + r0 + 3 < N) T[(row0 + r0 + 3) * 64 + c] = a3;
}

// Fused: A[n,:] = bias + sum_p wgt[p]*T[col[p],:]   (one wave / node, unroll 8)
//        + proj slice into out[n, 0:16]
//        + (layer 3) t4[n] = dot(A[n,:], W3)
template <int LAYER, bool WRITE_A, bool COMPUTE_T4>
__global__ __launch_bounds__(256) void k_agg_fused(
    const float* __restrict__ T,
    const int2* __restrict__ edges,
    const int* __restrict__ row_ptr,
    const float* __restrict__ bias,
    const float* __restrict__ conv_w,
    const float* __restrict__ conv_b,
    const float* __restrict__ W3,
    float* __restrict__ Aout,
    float* __restrict__ out,
    float* __restrict__ t4) {
    // conv_w slice [64][16], transposed + XOR-swizzled: element (j,c) at
    // (j<<4) + (c ^ ((j>>4)<<3))  -> 2-way banks on the read pattern (free)
    __shared__ float CWT[1024];
    const int tid = threadIdx.x;
    for (int idx = tid; idx < 1024; idx += 256) {
        int j = idx >> 4, c = idx & 15;
        CWT[(j << 4) + (c ^ ((j >> 4) << 3))] = conv_w[c * TOT + LAYER * 64 + j];
    }
    const int lane = tid & 63;
    const float bv = bias[lane];
    float w3v = 0.f;
    if constexpr (COMPUTE_T4) w3v = W3[lane];
    __syncthreads();

    const int n = (blockIdx.x * 256 + tid) >> 6;
    if (n >= N) return;

    const int p0 = __builtin_amdgcn_readfirstlane(row_ptr[n]);
    const int p1 = __builtin_amdgcn_readfirstlane(row_ptr[n + 1]);

    float acc0 = 0.f, acc1 = 0.f;
    for (int p = p0; p < p1; p += 8) {
        int2 e0 = edges[p + 0], e1 = edges[p + 1], e2 = edges[p + 2], e3 = edges[p + 3];
        int2 e4 = edges[p + 4], e5 = edges[p + 5], e6 = edges[p + 6], e7 = edges[p + 7];
        float t0 = T[e0.x * 64 + lane];
        float t1 = T[e1.x * 64 + lane];
        float t2 = T[e2.x * 64 + lane];
        float t3 = T[e3.x * 64 + lane];
        float t4r = T[e4.x * 64 + lane];
        float t5 = T[e5.x * 64 + lane];
        float t6 = T[e6.x * 64 + lane];
        float t7 = T[e7.x * 64 + lane];
        float w0 = __int_as_float(e0.y);
        float w1 = (p + 1 < p1) ? __int_as_float(e1.y) : 0.f;
        float w2 = (p + 2 < p1) ? __int_as_float(e2.y) : 0.f;
        float w3 = (p + 3 < p1) ? __int_as_float(e3.y) : 0.f;
        float w4 = (p + 4 < p1) ? __int_as_float(e4.y) : 0.f;
        float w5 = (p + 5 < p1) ? __int_as_float(e5.y) : 0.f;
        float w6 = (p + 6 < p1) ? __int_as_float(e6.y) : 0.f;
        float w7 = (p + 7 < p1) ? __int_as_float(e7.y) : 0.f;
        acc0 += w0 * t0; acc1 += w1 * t1;
        acc0 += w2 * t2; acc1 += w3 * t3;
        acc0 += w4 * t4r; acc1 += w5 * t5;
        acc0 += w6 * t6; acc1 += w7 * t7;
    }
    const float aval = acc0 + acc1 + bv;

    if constexpr (WRITE_A) Aout[n * 64 + lane] = aval;

    if constexpr (COMPUTE_T4) {
        float v = aval * w3v;
#pragma unroll
        for (int off = 32; off; off >>= 1) v += __shfl_xor(v, off);
        if (lane == 0) t4[n] = v;
    }

    // projection: lane = (c,g); partial dot over j = 16g..16g+15, reduce over g
    const int c = lane & 15, g = lane >> 4;
    float r = 0.f;
#pragma unroll
    for (int i = 0; i < 16; ++i) {
        int j = (g << 4) + i;
        float aj = __shfl(aval, j);
        r += aj * CWT[(j << 4) + (c ^ (g << 3))];
    }
    r += __shfl_xor(r, 16);
    r += __shfl_xor(r, 32);
    if (lane < 16) {
        int o = n * NC + c;
        out[o] = ((LAYER == 0) ? conv_b[c] : out[o]) + r;
    }
}

// h4 = b3 + agg(t4); out[n, :] += h4 * conv_w[:, 192]   (thread per node)
__global__ __launch_bounds__(256) void k_agg4_out(
    const float* __restrict__ t4, const int2* __restrict__ edges,
    const int* __restrict__ row_ptr, const float* __restrict__ b3,
    const float* __restrict__ conv_w, float* __restrict__ out) {
    int n = blockIdx.x * blockDim.x + threadIdx.x;
    if (n >= N) return;
    int p0 = row_ptr[n], p1 = row_ptr[n + 1];
    float a0 = 0.f, a1 = 0.f;
    for (int p = p0; p < p1; p += 4) {
        int2 e0 = edges[p + 0], e1 = edges[p + 1], e2 = edges[p + 2], e3 = edges[p + 3];
        float w0 = __int_as_float(e0.y);
        float w1 = (p + 1 < p1) ? __int_as_float(e1.y) : 0.f;
        float w2 = (p + 2 < p1) ? __int_as_float(e2.y) : 0.f;
        float w3 = (p + 3 < p1) ? __int_as_float(e3.y) : 0.f;
        a0 += w0 * t4[e0.x]; a1 += w1 * t4[e1.x];
        a0 += w2 * t4[e2.x]; a1 += w3 * t4[e3.x];
    }
    float h4 = a0 + a1 + b3[0];
    float4* o4 = (float4*)(out + n * NC);
#pragma unroll
    for (int k = 0; k < 4; ++k) {
        float4 v = o4[k];
        v.x += h4 * conv_w[(4 * k + 0) * TOT + 192];
        v.y += h4 * conv_w[(4 * k + 1) * TOT + 192];
        v.z += h4 * conv_w[(4 * k + 2) * TOT + 192];
        v.w += h4 * conv_w[(4 * k + 3) * TOT + 192];
        o4[k] = v;
    }
}

// ---------------- launch ----------------

extern "C" void kernel_launch(void* const* d_in, const int* in_sizes, int n_in,
                              void* d_out, int out_size, void* d_ws, size_t ws_size,
                              hipStream_t stream) {
    const float* x   = (const float*)d_in[0];
    const int*   ei  = (const int*)d_in[1];
    const int*   src = ei;
    const int*   dst = ei + E;
    const float* W0  = (const float*)d_in[3];
    const float* b0  = (const float*)d_in[4];
    const float* W1  = (const float*)d_in[5];
    const float* b1  = (const float*)d_in[6];
    const float* W2  = (const float*)d_in[7];
    const float* b2  = (const float*)d_in[8];
    const float* W3  = (const float*)d_in[9];
    const float* b3  = (const float*)d_in[10];
    const float* cw  = (const float*)d_in[11];
    const float* cb  = (const float*)d_in[12];
    float* out = (float*)d_out;

    char* p = (char*)d_ws;
    auto alloc = [&](size_t nbytes) {
        char* r = p;
        p += (nbytes + 255) & ~(size_t)255;
        return (void*)r;
    };
    int*   deg     = (int*)alloc((size_t)N * 4);
    int*   fill    = (int*)alloc((size_t)N * 4);
    int*   row_ptr = (int*)alloc((size_t)(N + 1) * 4);
    float* dinv    = (float*)alloc((size_t)N * 4);
    int*   part    = (int*)alloc((size_t)NB * 4);
    int2*  edges   = (int2*)alloc((size_t)(TE + 8) * 8);
    float* T       = (float*)alloc((size_t)N * 64 * 4);
    float* A       = (float*)alloc((size_t)N * 64 * 4);
    float* t4      = (float*)alloc((size_t)N * 4);

    // graph preprocessing (hierarchical scan: part -> scanpart -> scatter)
    k_init    <<<(N + 255) / 256, 256, 0, stream>>>(deg, fill, edges);
    k_count   <<<(E + 255) / 256, 256, 0, stream>>>(dst, deg);
    k_part    <<<NB, 256, 0, stream>>>(deg, part);
    k_scanpart<<<1, 256, 0, stream>>>(part);
    k_scatter <<<NB, 256, 0, stream>>>(deg, part, row_ptr, dinv);
    k_fill    <<<(TE + 255) / 256, 256, 0, stream>>>(src, dst, row_ptr, fill, dinv, edges);

    const int gemmGrid = (N + 15) / 16;
    const int aggGrid  = (N + 3) / 4;   // one wave / node, 4 waves / block

    // layer 1 (input x)
    k_gemm64<<<gemmGrid, 256, 0, stream>>>(x, W0, T);
    k_agg_fused<0, true, false><<<aggGrid, 256, 0, stream>>>(
        T, edges, row_ptr, b0, cw, cb, nullptr, A, out, nullptr);
    // layer 2
    k_gemm64<<<gemmGrid, 256, 0, stream>>>(A, W1, T);
    k_agg_fused<1, true, false><<<aggGrid, 256, 0, stream>>>(
        T, edges, row_ptr, b1, cw, cb, nullptr, A, out, nullptr);
    // layer 3 (also computes t4 = A3 . W3; A3 itself not needed afterwards)
    k_gemm64<<<gemmGrid, 256, 0, stream>>>(A, W2, T);
    k_agg_fused<2, false, true><<<aggGrid, 256, 0, stream>>>(
        T, edges, row_ptr, b2, cw, cb, W3, nullptr, out, t4);
    // layer 4 (H -> 1) aggregation + final column of projection
    k_agg4_out<<<(N + 255) / 256, 256, 0, stream>>>(t4, edges, row_ptr, b3, cw, out);
}

// Round 5
// 290.992 us; speedup vs baseline: 2.2580x; 1.2938x over previous
//
#include <hip/hip_runtime.h>
#include <math.h>

// Problem constants (fixed by the reference)
static constexpr int N    = 50000;   // nodes
static constexpr int E    = 800000;  // edges
static constexpr int TE   = E + N;   // edges + self loops
static constexpr int NC   = 16;      // conv1d channels
static constexpr int TOT  = 193;     // concat dim
static constexpr int NB   = (N + 255) / 256;  // 196 scan blocks

// ---------------- graph preprocessing ----------------

__global__ void k_init(int* __restrict__ deg, int* __restrict__ fill,
                       int2* __restrict__ edges) {
    int i = blockIdx.x * blockDim.x + threadIdx.x;
    if (i < N) { deg[i] = 1; fill[i] = 0; }   // deg starts at 1 (self loop)
    if (i < 8) edges[TE + i] = make_int2(0, 0);  // pad for unrolled overrun
}

__global__ void k_count(const int* __restrict__ dst, int* __restrict__ deg) {
    int e = blockIdx.x * blockDim.x + threadIdx.x;
    if (e < E) atomicAdd(&deg[dst[e]], 1);
}

// hierarchical scan, stage 1: per-256-chunk sums
__global__ __launch_bounds__(256) void k_part(const int* __restrict__ deg,
                                              int* __restrict__ part) {
    __shared__ int red[256];
    const int t = threadIdx.x;
    int i = blockIdx.x * 256 + t;
    int v = (i < N) ? deg[i] : 0;
    red[t] = v;
    __syncthreads();
#pragma unroll
    for (int off = 128; off; off >>= 1) {
        if (t < off) red[t] += red[t + off];
        __syncthreads();
    }
    if (t == 0) part[blockIdx.x] = red[0];
}

// stage 2: exclusive scan of the 196 partials (single small block)
__global__ __launch_bounds__(256) void k_scanpart(int* __restrict__ part) {
    __shared__ int s[256];
    const int t = threadIdx.x;
    int v = (t < NB) ? part[t] : 0;
    s[t] = v;
    __syncthreads();
#pragma unroll
    for (int off = 1; off < 256; off <<= 1) {
        int u = (t >= off) ? s[t - off] : 0;
        __syncthreads();
        s[t] += u;
        __syncthreads();
    }
    if (t < NB) part[t] = s[t] - v;  // exclusive prefix
}

// stage 3: local inclusive scan + scatter row_ptr; fused dinv = rsqrt(deg)
__global__ __launch_bounds__(256) void k_scatter(const int* __restrict__ deg,
                                                 const int* __restrict__ part,
                                                 int* __restrict__ row_ptr,
                                                 float* __restrict__ dinv) {
    __shared__ int s[256];
    const int t = threadIdx.x;
    int i = blockIdx.x * 256 + t;
    int v = (i < N) ? deg[i] : 0;
    s[t] = v;
    __syncthreads();
#pragma unroll
    for (int off = 1; off < 256; off <<= 1) {
        int u = (t >= off) ? s[t - off] : 0;
        __syncthreads();
        s[t] += u;
        __syncthreads();
    }
    if (i < N) {
        int base = part[blockIdx.x];
        row_ptr[i] = base + s[t] - v;
        dinv[i] = rsqrtf((float)v);           // deg >= 1 always (self loop)
        if (i == N - 1) row_ptr[N] = base + s[t];
    }
}

// scatter edges (+self loops) into CSR (by dst), packed {col, wgt-bits}
__global__ void k_fill(const int* __restrict__ src, const int* __restrict__ dst,
                       const int* __restrict__ row_ptr, int* __restrict__ fill,
                       const float* __restrict__ dinv,
                       int2* __restrict__ edges) {
    int idx = blockIdx.x * blockDim.x + threadIdx.x;
    if (idx < E) {
        int s = src[idx], d = dst[idx];
        int p = row_ptr[d] + atomicAdd(&fill[d], 1);
        edges[p] = make_int2(s, __float_as_int(dinv[s] * dinv[d]));
    } else if (idx < TE) {
        int i = idx - E;
        int p = row_ptr[i] + atomicAdd(&fill[i], 1);
        float dv = dinv[i];
        edges[p] = make_int2(i, __float_as_int(dv * dv));
    }
}

// ---------------- fused layer ----------------
// Using associativity: h_next = (S · h_prev) · W + b    (S = normalized adj)
// One wave per node:
//   1) gather: agg[lane] = sum_p wgt[p] * Hin[col[p], lane]        (unroll 8)
//   2) W-mult: h[lane]   = b[lane] + sum_k agg[k] * W[k][lane]
//      (agg row staged in LDS; broadcast float4 reads; W LDS-resident)
//   3) proj epilogue into out[n, 0:16]; optionally t4[n] = h . W3
// CWT layout: stride 17 (NOT a XOR swizzle — the old c^((j>>4)<<3) overflowed
// the 4-bit c range and wrote/read past the array; with stride 17 the banks
// for the read pattern (16g+17i+c mod 32) are 2-way worst case = free.
template <int LAYER, bool WRITE_A, bool COMPUTE_T4>
__global__ __launch_bounds__(256) void k_layer(
    const float* __restrict__ Hin,
    const int2* __restrict__ edges,
    const int* __restrict__ row_ptr,
    const float* __restrict__ W,
    const float* __restrict__ bias,
    const float* __restrict__ conv_w,
    const float* __restrict__ conv_b,
    const float* __restrict__ W3,
    float* __restrict__ Aout,
    float* __restrict__ out,
    float* __restrict__ t4) {
    __shared__ float Ws[64 * 64];     // W row-major: Ws[k*64+c]
    __shared__ float CWT[64 * 17];    // conv_w slice, padded stride 17
    __shared__ float AggS[4][64];     // per-wave agg row staging
    const int tid = threadIdx.x;
    for (int i = tid; i < 4096; i += 256) Ws[i] = W[i];
    for (int idx = tid; idx < 1024; idx += 256) {
        int j = idx >> 4, c = idx & 15;
        CWT[j * 17 + c] = conv_w[c * TOT + LAYER * 64 + j];
    }
    const int lane = tid & 63;
    const int w = tid >> 6;
    const float bv = bias[lane];
    float w3v = 0.f;
    if constexpr (COMPUTE_T4) w3v = W3[lane];
    __syncthreads();

    const int n = blockIdx.x * 4 + w;
    if (n >= N) return;

    const int p0 = __builtin_amdgcn_readfirstlane(row_ptr[n]);
    const int p1 = __builtin_amdgcn_readfirstlane(row_ptr[n + 1]);

    float acc0 = 0.f, acc1 = 0.f;
    for (int p = p0; p < p1; p += 8) {
        int2 e0 = edges[p + 0], e1 = edges[p + 1], e2 = edges[p + 2], e3 = edges[p + 3];
        int2 e4 = edges[p + 4], e5 = edges[p + 5], e6 = edges[p + 6], e7 = edges[p + 7];
        float t0 = Hin[e0.x * 64 + lane];
        float t1 = Hin[e1.x * 64 + lane];
        float t2 = Hin[e2.x * 64 + lane];
        float t3 = Hin[e3.x * 64 + lane];
        float t4r = Hin[e4.x * 64 + lane];
        float t5 = Hin[e5.x * 64 + lane];
        float t6 = Hin[e6.x * 64 + lane];
        float t7 = Hin[e7.x * 64 + lane];
        float w0 = __int_as_float(e0.y);
        float w1 = (p + 1 < p1) ? __int_as_float(e1.y) : 0.f;
        float w2 = (p + 2 < p1) ? __int_as_float(e2.y) : 0.f;
        float w3 = (p + 3 < p1) ? __int_as_float(e3.y) : 0.f;
        float w4 = (p + 4 < p1) ? __int_as_float(e4.y) : 0.f;
        float w5 = (p + 5 < p1) ? __int_as_float(e5.y) : 0.f;
        float w6 = (p + 6 < p1) ? __int_as_float(e6.y) : 0.f;
        float w7 = (p + 7 < p1) ? __int_as_float(e7.y) : 0.f;
        acc0 += w0 * t0; acc1 += w1 * t1;
        acc0 += w2 * t2; acc1 += w3 * t3;
        acc0 += w4 * t4r; acc1 += w5 * t5;
        acc0 += w6 * t6; acc1 += w7 * t7;
    }
    AggS[w][lane] = acc0 + acc1;   // wave-local write, read back below

    // h[lane] = b[lane] + sum_k agg[k] * W[k][lane]
    float hv = bv;
    const float4* arow = (const float4*)&AggS[w][0];
#pragma unroll
    for (int j = 0; j < 16; ++j) {
        float4 a4 = arow[j];           // uniform-address broadcast read
        hv += a4.x * Ws[(4 * j + 0) * 64 + lane];
        hv += a4.y * Ws[(4 * j + 1) * 64 + lane];
        hv += a4.z * Ws[(4 * j + 2) * 64 + lane];
        hv += a4.w * Ws[(4 * j + 3) * 64 + lane];
    }

    if constexpr (WRITE_A) Aout[n * 64 + lane] = hv;

    if constexpr (COMPUTE_T4) {
        float v = hv * w3v;
#pragma unroll
        for (int off = 32; off; off >>= 1) v += __shfl_xor(v, off);
        if (lane == 0) t4[n] = v;
    }

    // projection: lane = (c,g); partial dot over j = 16g..16g+15, reduce over g
    const int c = lane & 15, g = lane >> 4;
    float r = 0.f;
#pragma unroll
    for (int i = 0; i < 16; ++i) {
        int j = (g << 4) + i;
        float aj = __shfl(hv, j);
        r += aj * CWT[j * 17 + c];
    }
    r += __shfl_xor(r, 16);
    r += __shfl_xor(r, 32);
    if (lane < 16) {
        int o = n * NC + c;
        out[o] = ((LAYER == 0) ? conv_b[c] : out[o]) + r;
    }
}

// h4 = b3 + agg(t4); out[n, :] += h4 * conv_w[:, 192]   (thread per node)
__global__ __launch_bounds__(256) void k_agg4_out(
    const float* __restrict__ t4, const int2* __restrict__ edges,
    const int* __restrict__ row_ptr, const float* __restrict__ b3,
    const float* __restrict__ conv_w, float* __restrict__ out) {
    int n = blockIdx.x * blockDim.x + threadIdx.x;
    if (n >= N) return;
    int p0 = row_ptr[n], p1 = row_ptr[n + 1];
    float a0 = 0.f, a1 = 0.f;
    for (int p = p0; p < p1; p += 4) {
        int2 e0 = edges[p + 0], e1 = edges[p + 1], e2 = edges[p + 2], e3 = edges[p + 3];
        float w0 = __int_as_float(e0.y);
        float w1 = (p + 1 < p1) ? __int_as_float(e1.y) : 0.f;
        float w2 = (p + 2 < p1) ? __int_as_float(e2.y) : 0.f;
        float w3 = (p + 3 < p1) ? __int_as_float(e3.y) : 0.f;
        a0 += w0 * t4[e0.x]; a1 += w1 * t4[e1.x];
        a0 += w2 * t4[e2.x]; a1 += w3 * t4[e3.x];
    }
    float h4 = a0 + a1 + b3[0];
    float4* o4 = (float4*)(out + n * NC);
#pragma unroll
    for (int k = 0; k < 4; ++k) {
        float4 v = o4[k];
        v.x += h4 * conv_w[(4 * k + 0) * TOT + 192];
        v.y += h4 * conv_w[(4 * k + 1) * TOT + 192];
        v.z += h4 * conv_w[(4 * k + 2) * TOT + 192];
        v.w += h4 * conv_w[(4 * k + 3) * TOT + 192];
        o4[k] = v;
    }
}

// ---------------- launch ----------------

extern "C" void kernel_launch(void* const* d_in, const int* in_sizes, int n_in,
                              void* d_out, int out_size, void* d_ws, size_t ws_size,
                              hipStream_t stream) {
    const float* x   = (const float*)d_in[0];
    const int*   ei  = (const int*)d_in[1];
    const int*   src = ei;
    const int*   dst = ei + E;
    const float* W0  = (const float*)d_in[3];
    const float* b0  = (const float*)d_in[4];
    const float* W1  = (const float*)d_in[5];
    const float* b1  = (const float*)d_in[6];
    const float* W2  = (const float*)d_in[7];
    const float* b2  = (const float*)d_in[8];
    const float* W3  = (const float*)d_in[9];
    const float* b3  = (const float*)d_in[10];
    const float* cw  = (const float*)d_in[11];
    const float* cb  = (const float*)d_in[12];
    float* out = (float*)d_out;

    char* p = (char*)d_ws;
    auto alloc = [&](size_t nbytes) {
        char* r = p;
        p += (nbytes + 255) & ~(size_t)255;
        return (void*)r;
    };
    int*   deg     = (int*)alloc((size_t)N * 4);
    int*   fill    = (int*)alloc((size_t)N * 4);
    int*   row_ptr = (int*)alloc((size_t)(N + 1) * 4);
    float* dinv    = (float*)alloc((size_t)N * 4);
    int*   part    = (int*)alloc((size_t)NB * 4);
    int2*  edges   = (int2*)alloc((size_t)(TE + 8) * 8);
    float* A       = (float*)alloc((size_t)N * 64 * 4);
    float* B       = (float*)alloc((size_t)N * 64 * 4);
    float* t4      = (float*)alloc((size_t)N * 4);

    // graph preprocessing (hierarchical scan: part -> scanpart -> scatter)
    k_init    <<<(N + 255) / 256, 256, 0, stream>>>(deg, fill, edges);
    k_count   <<<(E + 255) / 256, 256, 0, stream>>>(dst, deg);
    k_part    <<<NB, 256, 0, stream>>>(deg, part);
    k_scanpart<<<1, 256, 0, stream>>>(part);
    k_scatter <<<NB, 256, 0, stream>>>(deg, part, row_ptr, dinv);
    k_fill    <<<(TE + 255) / 256, 256, 0, stream>>>(src, dst, row_ptr, fill, dinv, edges);

    const int layerGrid = (N + 3) / 4;   // one wave / node, 4 waves / block

    // layer 1: h1 = (S x) W0 + b0
    k_layer<0, true, false><<<layerGrid, 256, 0, stream>>>(
        x, edges, row_ptr, W0, b0, cw, cb, nullptr, A, out, nullptr);
    // layer 2: h2 = (S h1) W1 + b1
    k_layer<1, true, false><<<layerGrid, 256, 0, stream>>>(
        A, edges, row_ptr, W1, b1, cw, cb, nullptr, B, out, nullptr);
    // layer 3: h3 = (S h2) W2 + b2 ; t4 = h3 . W3  (h3 itself not stored)
    k_layer<2, false, true><<<layerGrid, 256, 0, stream>>>(
        B, edges, row_ptr, W2, b2, cw, cb, W3, nullptr, out, t4);
    // layer 4 (H -> 1) aggregation + final column of projection
    k_agg4_out<<<(N + 255) / 256, 256, 0, stream>>>(t4, edges, row_ptr, b3, cw, out);
}

// Round 6
// 265.405 us; speedup vs baseline: 2.4757x; 1.0964x over previous
//
#include <hip/hip_runtime.h>
#include <math.h>

// Problem constants (fixed by the reference)
static constexpr int N    = 50000;   // nodes
static constexpr int E    = 800000;  // edges
static constexpr int TE   = E + N;   // edges + self loops
static constexpr int NC   = 16;      // conv1d channels
static constexpr int TOT  = 193;     // concat dim
static constexpr int NB   = (N + 255) / 256;  // 196 scan blocks

// K-buffer layout (floats)
static constexpr int KQ1 = 0;      // Q1[64][16] = W0 . cw1^T
static constexpr int KQ2 = 1024;   // Q2[64][16] = (W0W1) . cw2^T
static constexpr int KQ3 = 2048;   // Q3[64][16] = (W0W1W2) . cw3^T
static constexpr int KV  = 3072;   // v[64] = (W0W1W2) W3
static constexpr int KU1 = 3136;   // u1[16] = (b0W1)cw2^T + (b1W2)cw3^T
static constexpr int KU2 = 3152;   // u2[16] = (b0W1W2)cw3^T
static constexpr int KD  = 3168;   // d[16]  = b0 cw1^T + b1 cw2^T + b2 cw3^T + cb
static constexpr int KSC = 3184;   // alpha=(b0W1W2)W3, beta=(b1W2)W3, gamma=b2.W3
static constexpr int KSZ = 3200;

// ---------------- graph preprocessing ----------------

__global__ void k_init(int* __restrict__ deg, int* __restrict__ fill,
                       int2* __restrict__ edges) {
    int i = blockIdx.x * blockDim.x + threadIdx.x;
    if (i < N) { deg[i] = 1; fill[i] = 0; }   // deg starts at 1 (self loop)
    if (i < 8) edges[TE + i] = make_int2(0, 0);  // pad for unrolled overrun
}

__global__ void k_count(const int* __restrict__ dst, int* __restrict__ deg) {
    int e = blockIdx.x * blockDim.x + threadIdx.x;
    if (e < E) atomicAdd(&deg[dst[e]], 1);
}

__global__ __launch_bounds__(256) void k_part(const int* __restrict__ deg,
                                              int* __restrict__ part) {
    __shared__ int red[256];
    const int t = threadIdx.x;
    int i = blockIdx.x * 256 + t;
    int v = (i < N) ? deg[i] : 0;
    red[t] = v;
    __syncthreads();
#pragma unroll
    for (int off = 128; off; off >>= 1) {
        if (t < off) red[t] += red[t + off];
        __syncthreads();
    }
    if (t == 0) part[blockIdx.x] = red[0];
}

__global__ __launch_bounds__(256) void k_scanpart(int* __restrict__ part) {
    __shared__ int s[256];
    const int t = threadIdx.x;
    int v = (t < NB) ? part[t] : 0;
    s[t] = v;
    __syncthreads();
#pragma unroll
    for (int off = 1; off < 256; off <<= 1) {
        int u = (t >= off) ? s[t - off] : 0;
        __syncthreads();
        s[t] += u;
        __syncthreads();
    }
    if (t < NB) part[t] = s[t] - v;  // exclusive prefix
}

__global__ __launch_bounds__(256) void k_scatter(const int* __restrict__ deg,
                                                 const int* __restrict__ part,
                                                 int* __restrict__ row_ptr,
                                                 float* __restrict__ dinv) {
    __shared__ int s[256];
    const int t = threadIdx.x;
    int i = blockIdx.x * 256 + t;
    int v = (i < N) ? deg[i] : 0;
    s[t] = v;
    __syncthreads();
#pragma unroll
    for (int off = 1; off < 256; off <<= 1) {
        int u = (t >= off) ? s[t - off] : 0;
        __syncthreads();
        s[t] += u;
        __syncthreads();
    }
    if (i < N) {
        int base = part[blockIdx.x];
        row_ptr[i] = base + s[t] - v;
        dinv[i] = rsqrtf((float)v);           // deg >= 1 always (self loop)
        if (i == N - 1) row_ptr[N] = base + s[t];
    }
}

__global__ void k_fill(const int* __restrict__ src, const int* __restrict__ dst,
                       const int* __restrict__ row_ptr, int* __restrict__ fill,
                       const float* __restrict__ dinv,
                       int2* __restrict__ edges) {
    int idx = blockIdx.x * blockDim.x + threadIdx.x;
    if (idx < E) {
        int s = src[idx], d = dst[idx];
        int p = row_ptr[d] + atomicAdd(&fill[d], 1);
        edges[p] = make_int2(s, __float_as_int(dinv[s] * dinv[d]));
    } else if (idx < TE) {
        int i = idx - E;
        int p = row_ptr[i] + atomicAdd(&fill[i], 1);
        float dv = dinv[i];
        edges[p] = make_int2(i, __float_as_int(dv * dv));
    }
}

// ---------------- setup: precompute combined weight products ----------------
// P2 = W0 W1, P3 = P2 W2 (LDS only); K = {Q1,Q2,Q3,v,u1,u2,d,alpha,beta,gamma}
__global__ __launch_bounds__(256) void k_setup(
    const float* __restrict__ W0, const float* __restrict__ b0,
    const float* __restrict__ W1, const float* __restrict__ b1,
    const float* __restrict__ W2, const float* __restrict__ b2,
    const float* __restrict__ W3, const float* __restrict__ b3,
    const float* __restrict__ cw, const float* __restrict__ cb,
    float* __restrict__ K) {
    __shared__ float A[4096], B[4096];
    __shared__ float rb1[64], rb2[64], rb12[64];
    const int t = threadIdx.x;
    const int k = t >> 2, j0 = (t & 3) * 16;
    float acc[16];

    for (int i = t; i < 4096; i += 256) A[i] = W1[i];
    __syncthreads();
    // P2 = W0 * W1 -> B
#pragma unroll
    for (int jj = 0; jj < 16; ++jj) acc[jj] = 0.f;
    for (int m = 0; m < 64; ++m) {
        float w = W0[k * 64 + m];
#pragma unroll
        for (int jj = 0; jj < 16; ++jj) acc[jj] += w * A[m * 64 + j0 + jj];
    }
    __syncthreads();
#pragma unroll
    for (int jj = 0; jj < 16; ++jj) B[k * 64 + j0 + jj] = acc[jj];
    for (int i = t; i < 4096; i += 256) A[i] = W2[i];
    __syncthreads();
    // P3 = P2 * W2 (to regs, then overwrite A)
#pragma unroll
    for (int jj = 0; jj < 16; ++jj) acc[jj] = 0.f;
    for (int m = 0; m < 64; ++m) {
        float w = B[k * 64 + m];
#pragma unroll
        for (int jj = 0; jj < 16; ++jj) acc[jj] += w * A[m * 64 + j0 + jj];
    }
    __syncthreads();
#pragma unroll
    for (int jj = 0; jj < 16; ++jj) A[k * 64 + j0 + jj] = acc[jj];
    // rb1 = b0 W1 ; rb2 = b1 W2   (from global W's)
    if (t < 64) {
        float a1 = 0.f, a2 = 0.f;
        for (int m = 0; m < 64; ++m) {
            a1 += b0[m] * W1[m * 64 + t];
            a2 += b1[m] * W2[m * 64 + t];
        }
        rb1[t] = a1; rb2[t] = a2;
    }
    __syncthreads();
    if (t < 64) {
        float a = 0.f;
        for (int m = 0; m < 64; ++m) a += rb1[m] * W2[m * 64 + t];
        rb12[t] = a;
    }
    __syncthreads();

    // Q1/Q2/Q3: thread handles (kq = t>>2, 4 c's)
    {
        const int kq = t >> 2, c0 = (t & 3) * 4;
        float q1[4] = {0,0,0,0}, q2[4] = {0,0,0,0}, q3[4] = {0,0,0,0};
        for (int j = 0; j < 64; ++j) {
            float w0 = W0[kq * 64 + j], p2 = B[kq * 64 + j], p3 = A[kq * 64 + j];
#pragma unroll
            for (int cc = 0; cc < 4; ++cc) {
                q1[cc] += w0 * cw[(c0 + cc) * TOT + j];
                q2[cc] += p2 * cw[(c0 + cc) * TOT + 64 + j];
                q3[cc] += p3 * cw[(c0 + cc) * TOT + 128 + j];
            }
        }
#pragma unroll
        for (int cc = 0; cc < 4; ++cc) {
            K[KQ1 + kq * 16 + c0 + cc] = q1[cc];
            K[KQ2 + kq * 16 + c0 + cc] = q2[cc];
            K[KQ3 + kq * 16 + c0 + cc] = q3[cc];
        }
    }
    // v = P3 W3
    if (t < 64) {
        float a = 0.f;
        for (int j = 0; j < 64; ++j) a += A[t * 64 + j] * W3[j];
        K[KV + t] = a;
    }
    // u1, u2, d
    if (t < 16) {
        float a1 = 0.f, a2 = 0.f, ad = 0.f;
        for (int j = 0; j < 64; ++j) {
            a1 += rb1[j] * cw[t * TOT + 64 + j] + rb2[j] * cw[t * TOT + 128 + j];
            a2 += rb12[j] * cw[t * TOT + 128 + j];
            ad += b0[j] * cw[t * TOT + j] + b1[j] * cw[t * TOT + 64 + j]
                + b2[j] * cw[t * TOT + 128 + j];
        }
        K[KU1 + t] = a1; K[KU2 + t] = a2; K[KD + t] = ad + cb[t];
    }
    if (t == 0) {
        float al = 0.f, be = 0.f, ga = 0.f;
        for (int j = 0; j < 64; ++j) {
            al += rb12[j] * W3[j]; be += rb2[j] * W3[j]; ga += b2[j] * W3[j];
        }
        K[KSC + 0] = al; K[KSC + 1] = be; K[KSC + 2] = ga;
    }
}

// ---------------- fused layer (M-basis: no per-node W multiply) ------------
// LAYER 0: M1 = S x       ; s1[n] = row-sum(S) ; out  = d + M1.Q1
// LAYER 1: M2 = S M1      ; s2 = S s1          ; out += M2.Q2
// LAYER 2: (M3 = S M2 in regs only) ; t4 = M3.v + a*s2 + b*s1 + g ;
//          out += M3.Q3 + s1*u1 + s2*u2
template <int LAYER>
__global__ __launch_bounds__(256) void k_layer(
    const float* __restrict__ Min,
    const int2* __restrict__ edges,
    const int* __restrict__ row_ptr,
    const float* __restrict__ K,
    const float* __restrict__ s1in,
    const float* __restrict__ s2in,
    float* __restrict__ Mout,
    float* __restrict__ s_out,
    float* __restrict__ t4,
    float* __restrict__ out) {
    __shared__ float QT[64 * 17];   // Q_LAYER, padded stride 17 (2-way banks max)
    const int tid = threadIdx.x;
    constexpr int KQ = (LAYER == 0) ? KQ1 : (LAYER == 1) ? KQ2 : KQ3;
    for (int i = tid; i < 1024; i += 256) {
        int j = i >> 4, c = i & 15;
        QT[j * 17 + c] = K[KQ + i];
    }
    const int lane = tid & 63;
    const int w = tid >> 6;
    float vv = 0.f;
    if constexpr (LAYER == 2) vv = K[KV + lane];
    __syncthreads();

    const int n = blockIdx.x * 4 + w;
    if (n >= N) return;

    const int p0 = __builtin_amdgcn_readfirstlane(row_ptr[n]);
    const int p1 = __builtin_amdgcn_readfirstlane(row_ptr[n + 1]);

    float acc0 = 0.f, acc1 = 0.f, accs = 0.f;
    for (int p = p0; p < p1; p += 8) {
        int2 e0 = edges[p + 0], e1 = edges[p + 1], e2 = edges[p + 2], e3 = edges[p + 3];
        int2 e4 = edges[p + 4], e5 = edges[p + 5], e6 = edges[p + 6], e7 = edges[p + 7];
        float t0 = Min[e0.x * 64 + lane];
        float t1 = Min[e1.x * 64 + lane];
        float t2 = Min[e2.x * 64 + lane];
        float t3 = Min[e3.x * 64 + lane];
        float t4r = Min[e4.x * 64 + lane];
        float t5 = Min[e5.x * 64 + lane];
        float t6 = Min[e6.x * 64 + lane];
        float t7 = Min[e7.x * 64 + lane];
        float w0 = __int_as_float(e0.y);
        float w1 = (p + 1 < p1) ? __int_as_float(e1.y) : 0.f;
        float w2 = (p + 2 < p1) ? __int_as_float(e2.y) : 0.f;
        float w3 = (p + 3 < p1) ? __int_as_float(e3.y) : 0.f;
        float w4 = (p + 4 < p1) ? __int_as_float(e4.y) : 0.f;
        float w5 = (p + 5 < p1) ? __int_as_float(e5.y) : 0.f;
        float w6 = (p + 6 < p1) ? __int_as_float(e6.y) : 0.f;
        float w7 = (p + 7 < p1) ? __int_as_float(e7.y) : 0.f;
        if constexpr (LAYER == 0)
            accs += ((w0 + w1) + (w2 + w3)) + ((w4 + w5) + (w6 + w7));
        acc0 += w0 * t0; acc1 += w1 * t1;
        acc0 += w2 * t2; acc1 += w3 * t3;
        acc0 += w4 * t4r; acc1 += w5 * t5;
        acc0 += w6 * t6; acc1 += w7 * t7;
    }
    const float acc = acc0 + acc1;

    if constexpr (LAYER < 2) Mout[n * 64 + lane] = acc;
    if constexpr (LAYER == 0) {
        if (lane == 0) s_out[n] = accs;   // accs uniform across lanes
    }
    if constexpr (LAYER == 1) {
        // s2[n] = sum_p wgt * s1[col]   (edges spread across lanes)
        float ss = 0.f;
        for (int p = p0 + lane; p < p1; p += 64) {
            int2 e = edges[p];
            ss += __int_as_float(e.y) * s1in[e.x];
        }
#pragma unroll
        for (int off = 32; off; off >>= 1) ss += __shfl_xor(ss, off);
        if (lane == 0) s_out[n] = ss;
    }

    float s1n = 0.f, s2n = 0.f;
    if constexpr (LAYER == 2) {
        s1n = s1in[n]; s2n = s2in[n];
        float tv = acc * vv;
#pragma unroll
        for (int off = 32; off; off >>= 1) tv += __shfl_xor(tv, off);
        if (lane == 0)
            t4[n] = tv + K[KSC + 0] * s2n + K[KSC + 1] * s1n + K[KSC + 2];
    }

    // projection: lane = (c,g); partial dot over j = 16g..16g+15, reduce over g
    const int c = lane & 15, g = lane >> 4;
    float r = 0.f;
#pragma unroll
    for (int i = 0; i < 16; ++i) {
        int j = (g << 4) + i;
        float aj = __shfl(acc, j);
        r += aj * QT[j * 17 + c];
    }
    r += __shfl_xor(r, 16);
    r += __shfl_xor(r, 32);
    if (lane < 16) {
        int o = n * NC + c;
        if constexpr (LAYER == 0) {
            out[o] = K[KD + c] + r;
        } else if constexpr (LAYER == 1) {
            out[o] += r;
        } else {
            out[o] += r + s1n * K[KU1 + c] + s2n * K[KU2 + c];
        }
    }
}

// h4 = b3 + agg(t4); out[n, :] += h4 * conv_w[:, 192]   (thread per node)
__global__ __launch_bounds__(256) void k_agg4_out(
    const float* __restrict__ t4, const int2* __restrict__ edges,
    const int* __restrict__ row_ptr, const float* __restrict__ b3,
    const float* __restrict__ conv_w, float* __restrict__ out) {
    int n = blockIdx.x * blockDim.x + threadIdx.x;
    if (n >= N) return;
    int p0 = row_ptr[n], p1 = row_ptr[n + 1];
    float a0 = 0.f, a1 = 0.f;
    for (int p = p0; p < p1; p += 4) {
        int2 e0 = edges[p + 0], e1 = edges[p + 1], e2 = edges[p + 2], e3 = edges[p + 3];
        float w0 = __int_as_float(e0.y);
        float w1 = (p + 1 < p1) ? __int_as_float(e1.y) : 0.f;
        float w2 = (p + 2 < p1) ? __int_as_float(e2.y) : 0.f;
        float w3 = (p + 3 < p1) ? __int_as_float(e3.y) : 0.f;
        a0 += w0 * t4[e0.x]; a1 += w1 * t4[e1.x];
        a0 += w2 * t4[e2.x]; a1 += w3 * t4[e3.x];
    }
    float h4 = a0 + a1 + b3[0];
    float4* o4 = (float4*)(out + n * NC);
#pragma unroll
    for (int k = 0; k < 4; ++k) {
        float4 v = o4[k];
        v.x += h4 * conv_w[(4 * k + 0) * TOT + 192];
        v.y += h4 * conv_w[(4 * k + 1) * TOT + 192];
        v.z += h4 * conv_w[(4 * k + 2) * TOT + 192];
        v.w += h4 * conv_w[(4 * k + 3) * TOT + 192];
        o4[k] = v;
    }
}

// ---------------- launch ----------------

extern "C" void kernel_launch(void* const* d_in, const int* in_sizes, int n_in,
                              void* d_out, int out_size, void* d_ws, size_t ws_size,
                              hipStream_t stream) {
    const float* x   = (const float*)d_in[0];
    const int*   ei  = (const int*)d_in[1];
    const int*   src = ei;
    const int*   dst = ei + E;
    const float* W0  = (const float*)d_in[3];
    const float* b0  = (const float*)d_in[4];
    const float* W1  = (const float*)d_in[5];
    const float* b1  = (const float*)d_in[6];
    const float* W2  = (const float*)d_in[7];
    const float* b2  = (const float*)d_in[8];
    const float* W3  = (const float*)d_in[9];
    const float* b3  = (const float*)d_in[10];
    const float* cw  = (const float*)d_in[11];
    const float* cb  = (const float*)d_in[12];
    float* out = (float*)d_out;

    char* p = (char*)d_ws;
    auto alloc = [&](size_t nbytes) {
        char* r = p;
        p += (nbytes + 255) & ~(size_t)255;
        return (void*)r;
    };
    int*   deg     = (int*)alloc((size_t)N * 4);
    int*   fill    = (int*)alloc((size_t)N * 4);
    int*   row_ptr = (int*)alloc((size_t)(N + 1) * 4);
    float* dinv    = (float*)alloc((size_t)N * 4);
    int*   part    = (int*)alloc((size_t)NB * 4);
    int2*  edges   = (int2*)alloc((size_t)(TE + 8) * 8);
    float* M1      = (float*)alloc((size_t)N * 64 * 4);
    float* M2      = (float*)alloc((size_t)N * 64 * 4);
    float* s1      = (float*)alloc((size_t)N * 4);
    float* s2      = (float*)alloc((size_t)N * 4);
    float* t4      = (float*)alloc((size_t)N * 4);
    float* K       = (float*)alloc((size_t)KSZ * 4);

    // weight-product setup (independent of graph)
    k_setup<<<1, 256, 0, stream>>>(W0, b0, W1, b1, W2, b2, W3, b3, cw, cb, K);

    // graph preprocessing (hierarchical scan: part -> scanpart -> scatter)
    k_init    <<<(N + 255) / 256, 256, 0, stream>>>(deg, fill, edges);
    k_count   <<<(E + 255) / 256, 256, 0, stream>>>(dst, deg);
    k_part    <<<NB, 256, 0, stream>>>(deg, part);
    k_scanpart<<<1, 256, 0, stream>>>(part);
    k_scatter <<<NB, 256, 0, stream>>>(deg, part, row_ptr, dinv);
    k_fill    <<<(TE + 255) / 256, 256, 0, stream>>>(src, dst, row_ptr, fill, dinv, edges);

    const int layerGrid = (N + 3) / 4;   // one wave / node, 4 waves / block

    k_layer<0><<<layerGrid, 256, 0, stream>>>(
        x, edges, row_ptr, K, nullptr, nullptr, M1, s1, nullptr, out);
    k_layer<1><<<layerGrid, 256, 0, stream>>>(
        M1, edges, row_ptr, K, s1, nullptr, M2, s2, nullptr, out);
    k_layer<2><<<layerGrid, 256, 0, stream>>>(
        M2, edges, row_ptr, K, s1, s2, nullptr, nullptr, t4, out);
    k_agg4_out<<<(N + 255) / 256, 256, 0, stream>>>(t4, edges, row_ptr, b3, cw, out);
}

// Round 7
// 239.078 us; speedup vs baseline: 2.7483x; 1.1101x over previous
//
#include <hip/hip_runtime.h>
#include <math.h>

// Problem constants (fixed by the reference)
static constexpr int N    = 50000;   // nodes
static constexpr int E    = 800000;  // edges
static constexpr int TE   = E + N;   // edges + self loops
static constexpr int NC   = 16;      // conv1d channels
static constexpr int TOT  = 193;     // concat dim
static constexpr int NB   = (N + 255) / 256;  // 196 scan blocks

// K-buffer layout (floats)
static constexpr int KQ1 = 0;      // Q1[64][16] = W0 . cw1^T
static constexpr int KQ2 = 1024;   // Q2[64][16] = (W0W1) . cw2^T
static constexpr int KQ3 = 2048;   // Q3[64][16] = (W0W1) . (W2 . cw3^T)
static constexpr int KV  = 3072;   // v[64] = (W0W1) . (W2 W3)
static constexpr int KU1 = 3136;   // u1[16] = (b0W1)cw2^T + (b1W2)cw3^T
static constexpr int KU2 = 3152;   // u2[16] = (b0W1W2)cw3^T
static constexpr int KD  = 3168;   // d[16]  = b0 cw1^T + b1 cw2^T + b2 cw3^T + cb
static constexpr int KSC = 3184;   // alpha=(b0W1W2)W3, beta=(b1W2)W3, gamma=b2.W3
static constexpr int KSZ = 3200;

// ---------------- graph preprocessing ----------------

__global__ void k_init(int* __restrict__ deg, int* __restrict__ fill,
                       int2* __restrict__ edges) {
    int i = blockIdx.x * blockDim.x + threadIdx.x;
    if (i < N) { deg[i] = 1; fill[i] = 0; }   // deg starts at 1 (self loop)
    if (i < 8) edges[TE + i] = make_int2(0, 0);  // pad for unrolled overrun
}

__global__ void k_count(const int* __restrict__ dst, int* __restrict__ deg) {
    int e = blockIdx.x * blockDim.x + threadIdx.x;
    if (e < E) atomicAdd(&deg[dst[e]], 1);
}

__global__ __launch_bounds__(256) void k_part(const int* __restrict__ deg,
                                              int* __restrict__ part) {
    __shared__ int red[256];
    const int t = threadIdx.x;
    int i = blockIdx.x * 256 + t;
    int v = (i < N) ? deg[i] : 0;
    red[t] = v;
    __syncthreads();
#pragma unroll
    for (int off = 128; off; off >>= 1) {
        if (t < off) red[t] += red[t + off];
        __syncthreads();
    }
    if (t == 0) part[blockIdx.x] = red[0];
}

__global__ __launch_bounds__(256) void k_scanpart(int* __restrict__ part) {
    __shared__ int s[256];
    const int t = threadIdx.x;
    int v = (t < NB) ? part[t] : 0;
    s[t] = v;
    __syncthreads();
#pragma unroll
    for (int off = 1; off < 256; off <<= 1) {
        int u = (t >= off) ? s[t - off] : 0;
        __syncthreads();
        s[t] += u;
        __syncthreads();
    }
    if (t < NB) part[t] = s[t] - v;  // exclusive prefix
}

__global__ __launch_bounds__(256) void k_scatter(const int* __restrict__ deg,
                                                 const int* __restrict__ part,
                                                 int* __restrict__ row_ptr,
                                                 float* __restrict__ dinv) {
    __shared__ int s[256];
    const int t = threadIdx.x;
    int i = blockIdx.x * 256 + t;
    int v = (i < N) ? deg[i] : 0;
    s[t] = v;
    __syncthreads();
#pragma unroll
    for (int off = 1; off < 256; off <<= 1) {
        int u = (t >= off) ? s[t - off] : 0;
        __syncthreads();
        s[t] += u;
        __syncthreads();
    }
    if (i < N) {
        int base = part[blockIdx.x];
        row_ptr[i] = base + s[t] - v;
        dinv[i] = rsqrtf((float)v);           // deg >= 1 always (self loop)
        if (i == N - 1) row_ptr[N] = base + s[t];
    }
}

__global__ void k_fill(const int* __restrict__ src, const int* __restrict__ dst,
                       const int* __restrict__ row_ptr, int* __restrict__ fill,
                       const float* __restrict__ dinv,
                       int2* __restrict__ edges) {
    int idx = blockIdx.x * blockDim.x + threadIdx.x;
    if (idx < E) {
        int s = src[idx], d = dst[idx];
        int p = row_ptr[d] + atomicAdd(&fill[d], 1);
        edges[p] = make_int2(s, __float_as_int(dinv[s] * dinv[d]));
    } else if (idx < TE) {
        int i = idx - E;
        int p = row_ptr[i] + atomicAdd(&fill[i], 1);
        float dv = dinv[i];
        edges[p] = make_int2(i, __float_as_int(dv * dv));
    }
}

// ---------------- setup: precompute combined weight products ----------------
// All inputs staged in LDS first (coalesced), then 3 all-LDS compute phases.
// Associativity kills the sequential P3 stage: Q3 = P2(W2 C3), v = P2(W2 W3).
__global__ __launch_bounds__(256) void k_setup(
    const float* __restrict__ W0, const float* __restrict__ b0,
    const float* __restrict__ W1, const float* __restrict__ b1,
    const float* __restrict__ W2, const float* __restrict__ b2,
    const float* __restrict__ W3, const float* __restrict__ b3,
    const float* __restrict__ cw, const float* __restrict__ cb,
    float* __restrict__ K) {
    __shared__ float W0s[4096], W1s[4096], W2s[4096], P2s[4096];
    __shared__ float C1[1024], C2[1024], C3[1024], R3s[1024];
    __shared__ float W3s[64], b0s[64], b1s[64], b2s[64];
    __shared__ float r3[64], rb1[64], rb2[64], rb12[64];
    const int t = threadIdx.x;
    const int k = t >> 2, q = t & 3;

    // ---- stage (coalesced / small) ----
    for (int i = t; i < 4096; i += 256) {
        W0s[i] = W0[i]; W1s[i] = W1[i]; W2s[i] = W2[i];
    }
    for (int i = t; i < 1024; i += 256) {
        int j = i >> 4, c = i & 15;       // C[j][c] = cw[c, off + j]
        C1[i] = cw[c * TOT + j];
        C2[i] = cw[c * TOT + 64 + j];
        C3[i] = cw[c * TOT + 128 + j];
    }
    if (t < 64) { W3s[t] = W3[t]; b0s[t] = b0[t]; b1s[t] = b1[t]; b2s[t] = b2[t]; }
    __syncthreads();

    // ---- phase 1: P2 = W0 W1 ; R3 = W2 C3 ; r3 = W2 W3 ; rb1 = b0 W1 ; rb2 = b1 W2
    {
        const int j0 = q * 16;
        float acc[16];
#pragma unroll
        for (int jj = 0; jj < 16; ++jj) acc[jj] = 0.f;
        for (int m = 0; m < 64; ++m) {
            float w = W0s[k * 64 + m];
#pragma unroll
            for (int jj = 0; jj < 16; ++jj) acc[jj] += w * W1s[m * 64 + j0 + jj];
        }
#pragma unroll
        for (int jj = 0; jj < 16; ++jj) P2s[k * 64 + j0 + jj] = acc[jj];
    }
    {
        const int c0 = q * 4;
        float acc[4] = {0.f, 0.f, 0.f, 0.f};
        for (int j = 0; j < 64; ++j) {
            float w = W2s[k * 64 + j];
#pragma unroll
            for (int cc = 0; cc < 4; ++cc) acc[cc] += w * C3[j * 16 + c0 + cc];
        }
#pragma unroll
        for (int cc = 0; cc < 4; ++cc) R3s[k * 16 + c0 + cc] = acc[cc];
    }
    if (q == 0) {
        float a = 0.f;
        for (int j = 0; j < 64; ++j) a += W2s[k * 64 + j] * W3s[j];
        r3[k] = a;
    }
    if (q == 1) {
        float a = 0.f;
        for (int m = 0; m < 64; ++m) a += b0s[m] * W1s[m * 64 + k];
        rb1[k] = a;
    }
    if (q == 2) {
        float a = 0.f;
        for (int m = 0; m < 64; ++m) a += b1s[m] * W2s[m * 64 + k];
        rb2[k] = a;
    }
    __syncthreads();

    // ---- phase 2: Q1 = W0 C1 ; Q2 = P2 C2 ; Q3 = P2 R3 ; v = P2 r3 ; rb12 = rb1 W2
    {
        const int c0 = q * 4;
        float q1[4] = {0,0,0,0}, q2[4] = {0,0,0,0}, q3[4] = {0,0,0,0};
        for (int j = 0; j < 64; ++j) {
            float w0 = W0s[k * 64 + j], p2 = P2s[k * 64 + j];
#pragma unroll
            for (int cc = 0; cc < 4; ++cc) {
                q1[cc] += w0 * C1[j * 16 + c0 + cc];
                q2[cc] += p2 * C2[j * 16 + c0 + cc];
                q3[cc] += p2 * R3s[j * 16 + c0 + cc];
            }
        }
#pragma unroll
        for (int cc = 0; cc < 4; ++cc) {
            K[KQ1 + k * 16 + c0 + cc] = q1[cc];
            K[KQ2 + k * 16 + c0 + cc] = q2[cc];
            K[KQ3 + k * 16 + c0 + cc] = q3[cc];
        }
    }
    if (q == 3) {
        float a = 0.f;
        for (int j = 0; j < 64; ++j) a += P2s[k * 64 + j] * r3[j];
        K[KV + k] = a;
    }
    if (q == 0) {
        float a = 0.f;
        for (int m = 0; m < 64; ++m) a += rb1[m] * W2s[m * 64 + k];
        rb12[k] = a;
    }
    __syncthreads();

    // ---- phase 3: bias projections ----
    if (t < 16) {
        float a1 = 0.f, a2 = 0.f, ad = 0.f;
        for (int j = 0; j < 64; ++j) {
            a1 += rb1[j] * C2[j * 16 + t] + rb2[j] * C3[j * 16 + t];
            a2 += rb12[j] * C3[j * 16 + t];
            ad += b0s[j] * C1[j * 16 + t] + b1s[j] * C2[j * 16 + t]
                + b2s[j] * C3[j * 16 + t];
        }
        K[KU1 + t] = a1; K[KU2 + t] = a2; K[KD + t] = ad + cb[t];
    }
    if (t == 0) {
        float al = 0.f, be = 0.f, ga = 0.f;
        for (int j = 0; j < 64; ++j) {
            al += rb12[j] * W3s[j]; be += rb2[j] * W3s[j]; ga += b2s[j] * W3s[j];
        }
        K[KSC + 0] = al; K[KSC + 1] = be; K[KSC + 2] = ga;
    }
}

// ---------------- fused layer (M-basis: no per-node W multiply) ------------
// LAYER 0: M1 = S x       ; s1[n] = row-sum(S) ; out  = d + M1.Q1
// LAYER 1: M2 = S M1      ; s2 = S s1          ; out += M2.Q2
// LAYER 2: (M3 = S M2 in regs only) ; t4 = M3.v + a*s2 + b*s1 + g ;
//          out += M3.Q3 + s1*u1 + s2*u2
template <int LAYER>
__global__ __launch_bounds__(256) void k_layer(
    const float* __restrict__ Min,
    const int2* __restrict__ edges,
    const int* __restrict__ row_ptr,
    const float* __restrict__ K,
    const float* __restrict__ s1in,
    const float* __restrict__ s2in,
    float* __restrict__ Mout,
    float* __restrict__ s_out,
    float* __restrict__ t4,
    float* __restrict__ out) {
    __shared__ float QT[64 * 17];   // Q_LAYER, padded stride 17 (2-way banks max)
    const int tid = threadIdx.x;
    constexpr int KQ = (LAYER == 0) ? KQ1 : (LAYER == 1) ? KQ2 : KQ3;
    for (int i = tid; i < 1024; i += 256) {
        int j = i >> 4, c = i & 15;
        QT[j * 17 + c] = K[KQ + i];
    }
    const int lane = tid & 63;
    const int w = tid >> 6;
    float vv = 0.f;
    if constexpr (LAYER == 2) vv = K[KV + lane];
    __syncthreads();

    const int n = blockIdx.x * 4 + w;
    if (n >= N) return;

    const int p0 = __builtin_amdgcn_readfirstlane(row_ptr[n]);
    const int p1 = __builtin_amdgcn_readfirstlane(row_ptr[n + 1]);

    float acc0 = 0.f, acc1 = 0.f, accs = 0.f;
    for (int p = p0; p < p1; p += 8) {
        int2 e0 = edges[p + 0], e1 = edges[p + 1], e2 = edges[p + 2], e3 = edges[p + 3];
        int2 e4 = edges[p + 4], e5 = edges[p + 5], e6 = edges[p + 6], e7 = edges[p + 7];
        float t0 = Min[e0.x * 64 + lane];
        float t1 = Min[e1.x * 64 + lane];
        float t2 = Min[e2.x * 64 + lane];
        float t3 = Min[e3.x * 64 + lane];
        float t4r = Min[e4.x * 64 + lane];
        float t5 = Min[e5.x * 64 + lane];
        float t6 = Min[e6.x * 64 + lane];
        float t7 = Min[e7.x * 64 + lane];
        float w0 = __int_as_float(e0.y);
        float w1 = (p + 1 < p1) ? __int_as_float(e1.y) : 0.f;
        float w2 = (p + 2 < p1) ? __int_as_float(e2.y) : 0.f;
        float w3 = (p + 3 < p1) ? __int_as_float(e3.y) : 0.f;
        float w4 = (p + 4 < p1) ? __int_as_float(e4.y) : 0.f;
        float w5 = (p + 5 < p1) ? __int_as_float(e5.y) : 0.f;
        float w6 = (p + 6 < p1) ? __int_as_float(e6.y) : 0.f;
        float w7 = (p + 7 < p1) ? __int_as_float(e7.y) : 0.f;
        if constexpr (LAYER == 0)
            accs += ((w0 + w1) + (w2 + w3)) + ((w4 + w5) + (w6 + w7));
        acc0 += w0 * t0; acc1 += w1 * t1;
        acc0 += w2 * t2; acc1 += w3 * t3;
        acc0 += w4 * t4r; acc1 += w5 * t5;
        acc0 += w6 * t6; acc1 += w7 * t7;
    }
    const float acc = acc0 + acc1;

    if constexpr (LAYER < 2) Mout[n * 64 + lane] = acc;
    if constexpr (LAYER == 0) {
        if (lane == 0) s_out[n] = accs;   // accs uniform across lanes
    }
    if constexpr (LAYER == 1) {
        // s2[n] = sum_p wgt * s1[col]   (edges spread across lanes)
        float ss = 0.f;
        for (int p = p0 + lane; p < p1; p += 64) {
            int2 e = edges[p];
            ss += __int_as_float(e.y) * s1in[e.x];
        }
#pragma unroll
        for (int off = 32; off; off >>= 1) ss += __shfl_xor(ss, off);
        if (lane == 0) s_out[n] = ss;
    }

    float s1n = 0.f, s2n = 0.f;
    if constexpr (LAYER == 2) {
        s1n = s1in[n]; s2n = s2in[n];
        float tv = acc * vv;
#pragma unroll
        for (int off = 32; off; off >>= 1) tv += __shfl_xor(tv, off);
        if (lane == 0)
            t4[n] = tv + K[KSC + 0] * s2n + K[KSC + 1] * s1n + K[KSC + 2];
    }

    // projection: lane = (c,g); partial dot over j = 16g..16g+15, reduce over g
    const int c = lane & 15, g = lane >> 4;
    float r = 0.f;
#pragma unroll
    for (int i = 0; i < 16; ++i) {
        int j = (g << 4) + i;
        float aj = __shfl(acc, j);
        r += aj * QT[j * 17 + c];
    }
    r += __shfl_xor(r, 16);
    r += __shfl_xor(r, 32);
    if (lane < 16) {
        int o = n * NC + c;
        if constexpr (LAYER == 0) {
            out[o] = K[KD + c] + r;
        } else if constexpr (LAYER == 1) {
            out[o] += r;
        } else {
            out[o] += r + s1n * K[KU1 + c] + s2n * K[KU2 + c];
        }
    }
}

// h4 = b3 + agg(t4); out[n, :] += h4 * conv_w[:, 192]   (thread per node)
__global__ __launch_bounds__(256) void k_agg4_out(
    const float* __restrict__ t4, const int2* __restrict__ edges,
    const int* __restrict__ row_ptr, const float* __restrict__ b3,
    const float* __restrict__ conv_w, float* __restrict__ out) {
    int n = blockIdx.x * blockDim.x + threadIdx.x;
    if (n >= N) return;
    int p0 = row_ptr[n], p1 = row_ptr[n + 1];
    float a0 = 0.f, a1 = 0.f;
    for (int p = p0; p < p1; p += 4) {
        int2 e0 = edges[p + 0], e1 = edges[p + 1], e2 = edges[p + 2], e3 = edges[p + 3];
        float w0 = __int_as_float(e0.y);
        float w1 = (p + 1 < p1) ? __int_as_float(e1.y) : 0.f;
        float w2 = (p + 2 < p1) ? __int_as_float(e2.y) : 0.f;
        float w3 = (p + 3 < p1) ? __int_as_float(e3.y) : 0.f;
        a0 += w0 * t4[e0.x]; a1 += w1 * t4[e1.x];
        a0 += w2 * t4[e2.x]; a1 += w3 * t4[e3.x];
    }
    float h4 = a0 + a1 + b3[0];
    float4* o4 = (float4*)(out + n * NC);
#pragma unroll
    for (int k = 0; k < 4; ++k) {
        float4 v = o4[k];
        v.x += h4 * conv_w[(4 * k + 0) * TOT + 192];
        v.y += h4 * conv_w[(4 * k + 1) * TOT + 192];
        v.z += h4 * conv_w[(4 * k + 2) * TOT + 192];
        v.w += h4 * conv_w[(4 * k + 3) * TOT + 192];
        o4[k] = v;
    }
}

// ---------------- launch ----------------

extern "C" void kernel_launch(void* const* d_in, const int* in_sizes, int n_in,
                              void* d_out, int out_size, void* d_ws, size_t ws_size,
                              hipStream_t stream) {
    const float* x   = (const float*)d_in[0];
    const int*   ei  = (const int*)d_in[1];
    const int*   src = ei;
    const int*   dst = ei + E;
    const float* W0  = (const float*)d_in[3];
    const float* b0  = (const float*)d_in[4];
    const float* W1  = (const float*)d_in[5];
    const float* b1  = (const float*)d_in[6];
    const float* W2  = (const float*)d_in[7];
    const float* b2  = (const float*)d_in[8];
    const float* W3  = (const float*)d_in[9];
    const float* b3  = (const float*)d_in[10];
    const float* cw  = (const float*)d_in[11];
    const float* cb  = (const float*)d_in[12];
    float* out = (float*)d_out;

    char* p = (char*)d_ws;
    auto alloc = [&](size_t nbytes) {
        char* r = p;
        p += (nbytes + 255) & ~(size_t)255;
        return (void*)r;
    };
    int*   deg     = (int*)alloc((size_t)N * 4);
    int*   fill    = (int*)alloc((size_t)N * 4);
    int*   row_ptr = (int*)alloc((size_t)(N + 1) * 4);
    float* dinv    = (float*)alloc((size_t)N * 4);
    int*   part    = (int*)alloc((size_t)NB * 4);
    int2*  edges   = (int2*)alloc((size_t)(TE + 8) * 8);
    float* M1      = (float*)alloc((size_t)N * 64 * 4);
    float* M2      = (float*)alloc((size_t)N * 64 * 4);
    float* s1      = (float*)alloc((size_t)N * 4);
    float* s2      = (float*)alloc((size_t)N * 4);
    float* t4      = (float*)alloc((size_t)N * 4);
    float* K       = (float*)alloc((size_t)KSZ * 4);

    // weight-product setup (independent of graph)
    k_setup<<<1, 256, 0, stream>>>(W0, b0, W1, b1, W2, b2, W3, b3, cw, cb, K);

    // graph preprocessing (hierarchical scan: part -> scanpart -> scatter)
    k_init    <<<(N + 255) / 256, 256, 0, stream>>>(deg, fill, edges);
    k_count   <<<(E + 255) / 256, 256, 0, stream>>>(dst, deg);
    k_part    <<<NB, 256, 0, stream>>>(deg, part);
    k_scanpart<<<1, 256, 0, stream>>>(part);
    k_scatter <<<NB, 256, 0, stream>>>(deg, part, row_ptr, dinv);
    k_fill    <<<(TE + 255) / 256, 256, 0, stream>>>(src, dst, row_ptr, fill, dinv, edges);

    const int layerGrid = (N + 3) / 4;   // one wave / node, 4 waves / block

    k_layer<0><<<layerGrid, 256, 0, stream>>>(
        x, edges, row_ptr, K, nullptr, nullptr, M1, s1, nullptr, out);
    k_layer<1><<<layerGrid, 256, 0, stream>>>(
        M1, edges, row_ptr, K, s1, nullptr, M2, s2, nullptr, out);
    k_layer<2><<<layerGrid, 256, 0, stream>>>(
        M2, edges, row_ptr, K, s1, s2, nullptr, nullptr, t4, out);
    k_agg4_out<<<(N + 255) / 256, 256, 0, stream>>>(t4, edges, row_ptr, b3, cw, out);
}

// Round 8
// 224.083 us; speedup vs baseline: 2.9322x; 1.0669x over previous
//
#include <hip/hip_runtime.h>
#include <math.h>

// Problem constants (fixed by the reference)
static constexpr int N    = 50000;   // nodes
static constexpr int E    = 800000;  // edges
static constexpr int TE   = E + N;   // edges + self loops
static constexpr int NC   = 16;      // conv1d channels
static constexpr int TOT  = 193;     // concat dim
static constexpr int NB   = (N + 255) / 256;  // 196 scan blocks

// K-buffer layout (floats)
static constexpr int KQ1 = 0;      // Q1[64][16] = W0 . cw1^T
static constexpr int KQ2 = 1024;   // Q2[64][16] = (W0W1) . cw2^T
static constexpr int KQ3 = 2048;   // Q3[64][16] = (W0W1) . (W2 . cw3^T)
static constexpr int KV  = 3072;   // v[64] = (W0W1) . (W2 W3)
static constexpr int KU1 = 3136;   // u1[16] = (b0W1)cw2^T + (b1W2)cw3^T
static constexpr int KU2 = 3152;   // u2[16] = (b0W1W2)cw3^T
static constexpr int KD  = 3168;   // d[16]  = b0 cw1^T + b1 cw2^T + b2 cw3^T + cb
static constexpr int KSC = 3184;   // alpha=(b0W1W2)W3, beta=(b1W2)W3, gamma=b2.W3
static constexpr int KSZ = 3200;

__device__ __forceinline__ float bf2f(unsigned short u) {
    union { unsigned int i; float f; } v; v.i = ((unsigned int)u) << 16; return v.f;
}
__device__ __forceinline__ unsigned short f2bf(float f) {
    union { float f; unsigned int i; } v; v.f = f;
    unsigned int b = v.i + 0x7FFFu + ((v.i >> 16) & 1u);   // RNE
    return (unsigned short)(b >> 16);
}

// ---------------- graph preprocessing ----------------

__global__ void k_init(int* __restrict__ deg, int* __restrict__ fill,
                       int2* __restrict__ edges) {
    int i = blockIdx.x * blockDim.x + threadIdx.x;
    if (i < N) { deg[i] = 1; fill[i] = 0; }   // deg starts at 1 (self loop)
    if (i < 16) edges[TE + i] = make_int2(0, 0);  // pad for prefetch overrun
}

__global__ void k_count(const int* __restrict__ dst, int* __restrict__ deg) {
    int e = blockIdx.x * blockDim.x + threadIdx.x;
    if (e < E) atomicAdd(&deg[dst[e]], 1);
}

__global__ __launch_bounds__(256) void k_part(const int* __restrict__ deg,
                                              int* __restrict__ part) {
    __shared__ int red[256];
    const int t = threadIdx.x;
    int i = blockIdx.x * 256 + t;
    int v = (i < N) ? deg[i] : 0;
    red[t] = v;
    __syncthreads();
#pragma unroll
    for (int off = 128; off; off >>= 1) {
        if (t < off) red[t] += red[t + off];
        __syncthreads();
    }
    if (t == 0) part[blockIdx.x] = red[0];
}

__global__ __launch_bounds__(256) void k_scanpart(int* __restrict__ part) {
    __shared__ int s[256];
    const int t = threadIdx.x;
    int v = (t < NB) ? part[t] : 0;
    s[t] = v;
    __syncthreads();
#pragma unroll
    for (int off = 1; off < 256; off <<= 1) {
        int u = (t >= off) ? s[t - off] : 0;
        __syncthreads();
        s[t] += u;
        __syncthreads();
    }
    if (t < NB) part[t] = s[t] - v;  // exclusive prefix
}

__global__ __launch_bounds__(256) void k_scatter(const int* __restrict__ deg,
                                                 const int* __restrict__ part,
                                                 int* __restrict__ row_ptr,
                                                 float* __restrict__ dinv) {
    __shared__ int s[256];
    const int t = threadIdx.x;
    int i = blockIdx.x * 256 + t;
    int v = (i < N) ? deg[i] : 0;
    s[t] = v;
    __syncthreads();
#pragma unroll
    for (int off = 1; off < 256; off <<= 1) {
        int u = (t >= off) ? s[t - off] : 0;
        __syncthreads();
        s[t] += u;
        __syncthreads();
    }
    if (i < N) {
        int base = part[blockIdx.x];
        row_ptr[i] = base + s[t] - v;
        dinv[i] = rsqrtf((float)v);           // deg >= 1 always (self loop)
        if (i == N - 1) row_ptr[N] = base + s[t];
    }
}

__global__ void k_fill(const int* __restrict__ src, const int* __restrict__ dst,
                       const int* __restrict__ row_ptr, int* __restrict__ fill,
                       const float* __restrict__ dinv,
                       int2* __restrict__ edges) {
    int idx = blockIdx.x * blockDim.x + threadIdx.x;
    if (idx < E) {
        int s = src[idx], d = dst[idx];
        int p = row_ptr[d] + atomicAdd(&fill[d], 1);
        edges[p] = make_int2(s, __float_as_int(dinv[s] * dinv[d]));
    } else if (idx < TE) {
        int i = idx - E;
        int p = row_ptr[i] + atomicAdd(&fill[i], 1);
        float dv = dinv[i];
        edges[p] = make_int2(i, __float_as_int(dv * dv));
    }
}

// x (fp32) -> xb (bf16), vectorized: 4 floats / thread
__global__ __launch_bounds__(256) void k_xbf(const float* __restrict__ x,
                                             ushort* __restrict__ xb) {
    int i = blockIdx.x * 256 + threadIdx.x;
    if (i * 4 >= N * 64) return;
    float4 v = ((const float4*)x)[i];
    ushort4 o;
    o.x = f2bf(v.x); o.y = f2bf(v.y); o.z = f2bf(v.z); o.w = f2bf(v.w);
    ((ushort4*)xb)[i] = o;
}

// ---------------- setup: precompute combined weight products ----------------
__global__ __launch_bounds__(256) void k_setup(
    const float* __restrict__ W0, const float* __restrict__ b0,
    const float* __restrict__ W1, const float* __restrict__ b1,
    const float* __restrict__ W2, const float* __restrict__ b2,
    const float* __restrict__ W3, const float* __restrict__ b3,
    const float* __restrict__ cw, const float* __restrict__ cb,
    float* __restrict__ K) {
    __shared__ float W0s[4096], W1s[4096], W2s[4096], P2s[4096];
    __shared__ float C1[1024], C2[1024], C3[1024], R3s[1024];
    __shared__ float W3s[64], b0s[64], b1s[64], b2s[64];
    __shared__ float r3[64], rb1[64], rb2[64], rb12[64];
    const int t = threadIdx.x;
    const int k = t >> 2, q = t & 3;

    for (int i = t; i < 4096; i += 256) {
        W0s[i] = W0[i]; W1s[i] = W1[i]; W2s[i] = W2[i];
    }
    for (int i = t; i < 1024; i += 256) {
        int j = i >> 4, c = i & 15;       // C[j][c] = cw[c, off + j]
        C1[i] = cw[c * TOT + j];
        C2[i] = cw[c * TOT + 64 + j];
        C3[i] = cw[c * TOT + 128 + j];
    }
    if (t < 64) { W3s[t] = W3[t]; b0s[t] = b0[t]; b1s[t] = b1[t]; b2s[t] = b2[t]; }
    __syncthreads();

    // phase 1: P2 = W0 W1 ; R3 = W2 C3 ; r3 = W2 W3 ; rb1 = b0 W1 ; rb2 = b1 W2
    {
        const int j0 = q * 16;
        float acc[16];
#pragma unroll
        for (int jj = 0; jj < 16; ++jj) acc[jj] = 0.f;
        for (int m = 0; m < 64; ++m) {
            float w = W0s[k * 64 + m];
#pragma unroll
            for (int jj = 0; jj < 16; ++jj) acc[jj] += w * W1s[m * 64 + j0 + jj];
        }
#pragma unroll
        for (int jj = 0; jj < 16; ++jj) P2s[k * 64 + j0 + jj] = acc[jj];
    }
    {
        const int c0 = q * 4;
        float acc[4] = {0.f, 0.f, 0.f, 0.f};
        for (int j = 0; j < 64; ++j) {
            float w = W2s[k * 64 + j];
#pragma unroll
            for (int cc = 0; cc < 4; ++cc) acc[cc] += w * C3[j * 16 + c0 + cc];
        }
#pragma unroll
        for (int cc = 0; cc < 4; ++cc) R3s[k * 16 + c0 + cc] = acc[cc];
    }
    if (q == 0) {
        float a = 0.f;
        for (int j = 0; j < 64; ++j) a += W2s[k * 64 + j] * W3s[j];
        r3[k] = a;
    }
    if (q == 1) {
        float a = 0.f;
        for (int m = 0; m < 64; ++m) a += b0s[m] * W1s[m * 64 + k];
        rb1[k] = a;
    }
    if (q == 2) {
        float a = 0.f;
        for (int m = 0; m < 64; ++m) a += b1s[m] * W2s[m * 64 + k];
        rb2[k] = a;
    }
    __syncthreads();

    // phase 2: Q1 = W0 C1 ; Q2 = P2 C2 ; Q3 = P2 R3 ; v = P2 r3 ; rb12 = rb1 W2
    {
        const int c0 = q * 4;
        float q1[4] = {0,0,0,0}, q2[4] = {0,0,0,0}, q3[4] = {0,0,0,0};
        for (int j = 0; j < 64; ++j) {
            float w0 = W0s[k * 64 + j], p2 = P2s[k * 64 + j];
#pragma unroll
            for (int cc = 0; cc < 4; ++cc) {
                q1[cc] += w0 * C1[j * 16 + c0 + cc];
                q2[cc] += p2 * C2[j * 16 + c0 + cc];
                q3[cc] += p2 * R3s[j * 16 + c0 + cc];
            }
        }
#pragma unroll
        for (int cc = 0; cc < 4; ++cc) {
            K[KQ1 + k * 16 + c0 + cc] = q1[cc];
            K[KQ2 + k * 16 + c0 + cc] = q2[cc];
            K[KQ3 + k * 16 + c0 + cc] = q3[cc];
        }
    }
    if (q == 3) {
        float a = 0.f;
        for (int j = 0; j < 64; ++j) a += P2s[k * 64 + j] * r3[j];
        K[KV + k] = a;
    }
    if (q == 0) {
        float a = 0.f;
        for (int m = 0; m < 64; ++m) a += rb1[m] * W2s[m * 64 + k];
        rb12[k] = a;
    }
    __syncthreads();

    // phase 3: bias projections
    if (t < 16) {
        float a1 = 0.f, a2 = 0.f, ad = 0.f;
        for (int j = 0; j < 64; ++j) {
            a1 += rb1[j] * C2[j * 16 + t] + rb2[j] * C3[j * 16 + t];
            a2 += rb12[j] * C3[j * 16 + t];
            ad += b0s[j] * C1[j * 16 + t] + b1s[j] * C2[j * 16 + t]
                + b2s[j] * C3[j * 16 + t];
        }
        K[KU1 + t] = a1; K[KU2 + t] = a2; K[KD + t] = ad + cb[t];
    }
    if (t == 0) {
        float al = 0.f, be = 0.f, ga = 0.f;
        for (int j = 0; j < 64; ++j) {
            al += rb12[j] * W3s[j]; be += rb2[j] * W3s[j]; ga += b2s[j] * W3s[j];
        }
        K[KSC + 0] = al; K[KSC + 1] = be; K[KSC + 2] = ga;
    }
}

// ---------------- fused layer (M-basis, bf16 tables, pipelined gather) -----
// LAYER 0: M1 = S xb      ; s1[n] = row-sum(S) ; out  = d + M1.Q1
// LAYER 1: M2 = S M1      ; s2 = S s1          ; out += M2.Q2
// LAYER 2: (M3 = S M2 regs only) ; t4 = M3.v + a*s2 + b*s1 + g ;
//          out += M3.Q3 + s1*u1 + s2*u2
template <int LAYER>
__global__ __launch_bounds__(256) void k_layer(
    const ushort* __restrict__ Min,      // bf16 rows [*,64]
    const int2* __restrict__ edges,
    const int* __restrict__ row_ptr,
    const float* __restrict__ K,
    const float* __restrict__ s1in,
    const float* __restrict__ s2in,
    ushort* __restrict__ Mout,           // bf16 rows [*,64]
    float* __restrict__ s_out,
    float* __restrict__ t4,
    float* __restrict__ out) {
    __shared__ float QT[64 * 17];   // Q_LAYER, padded stride 17 (2-way banks max)
    const int tid = threadIdx.x;
    constexpr int KQ = (LAYER == 0) ? KQ1 : (LAYER == 1) ? KQ2 : KQ3;
    for (int i = tid; i < 1024; i += 256) {
        int j = i >> 4, c = i & 15;
        QT[j * 17 + c] = K[KQ + i];
    }
    const int lane = tid & 63;
    const int w = tid >> 6;
    float vv = 0.f;
    if constexpr (LAYER == 2) vv = K[KV + lane];
    __syncthreads();

    const int n = blockIdx.x * 4 + w;
    if (n >= N) return;

    const int p0 = __builtin_amdgcn_readfirstlane(row_ptr[n]);
    const int p1 = __builtin_amdgcn_readfirstlane(row_ptr[n + 1]);

    float acc0 = 0.f, acc1 = 0.f, accs = 0.f;
    // software-pipelined: edge block i+1 loads overlap block i's gathers
    int2 e0 = edges[p0 + 0], e1 = edges[p0 + 1], e2 = edges[p0 + 2], e3 = edges[p0 + 3];
    int2 e4 = edges[p0 + 4], e5 = edges[p0 + 5], e6 = edges[p0 + 6], e7 = edges[p0 + 7];
    for (int p = p0; p < p1; p += 8) {
        // issue gathers for the current block (bf16: 128B/row)
        ushort g0 = Min[e0.x * 64 + lane];
        ushort g1 = Min[e1.x * 64 + lane];
        ushort g2 = Min[e2.x * 64 + lane];
        ushort g3 = Min[e3.x * 64 + lane];
        ushort g4 = Min[e4.x * 64 + lane];
        ushort g5 = Min[e5.x * 64 + lane];
        ushort g6 = Min[e6.x * 64 + lane];
        ushort g7 = Min[e7.x * 64 + lane];
        // prefetch next edge block (pad = 16 entries past TE)
        int2 f0 = edges[p + 8],  f1 = edges[p + 9],  f2 = edges[p + 10], f3 = edges[p + 11];
        int2 f4 = edges[p + 12], f5 = edges[p + 13], f6 = edges[p + 14], f7 = edges[p + 15];
        float w0 = __int_as_float(e0.y);
        float w1 = (p + 1 < p1) ? __int_as_float(e1.y) : 0.f;
        float w2 = (p + 2 < p1) ? __int_as_float(e2.y) : 0.f;
        float w3 = (p + 3 < p1) ? __int_as_float(e3.y) : 0.f;
        float w4 = (p + 4 < p1) ? __int_as_float(e4.y) : 0.f;
        float w5 = (p + 5 < p1) ? __int_as_float(e5.y) : 0.f;
        float w6 = (p + 6 < p1) ? __int_as_float(e6.y) : 0.f;
        float w7 = (p + 7 < p1) ? __int_as_float(e7.y) : 0.f;
        if constexpr (LAYER == 0)
            accs += ((w0 + w1) + (w2 + w3)) + ((w4 + w5) + (w6 + w7));
        acc0 += w0 * bf2f(g0); acc1 += w1 * bf2f(g1);
        acc0 += w2 * bf2f(g2); acc1 += w3 * bf2f(g3);
        acc0 += w4 * bf2f(g4); acc1 += w5 * bf2f(g5);
        acc0 += w6 * bf2f(g6); acc1 += w7 * bf2f(g7);
        e0 = f0; e1 = f1; e2 = f2; e3 = f3;
        e4 = f4; e5 = f5; e6 = f6; e7 = f7;
    }
    const float acc = acc0 + acc1;

    if constexpr (LAYER < 2) Mout[n * 64 + lane] = f2bf(acc);
    if constexpr (LAYER == 0) {
        if (lane == 0) s_out[n] = accs;   // accs uniform across lanes
    }
    if constexpr (LAYER == 1) {
        // s2[n] = sum_p wgt * s1[col]   (edges spread across lanes)
        float ss = 0.f;
        for (int p = p0 + lane; p < p1; p += 64) {
            int2 e = edges[p];
            ss += __int_as_float(e.y) * s1in[e.x];
        }
#pragma unroll
        for (int off = 32; off; off >>= 1) ss += __shfl_xor(ss, off);
        if (lane == 0) s_out[n] = ss;
    }

    float s1n = 0.f, s2n = 0.f;
    if constexpr (LAYER == 2) {
        s1n = s1in[n]; s2n = s2in[n];
        float tv = acc * vv;
#pragma unroll
        for (int off = 32; off; off >>= 1) tv += __shfl_xor(tv, off);
        if (lane == 0)
            t4[n] = tv + K[KSC + 0] * s2n + K[KSC + 1] * s1n + K[KSC + 2];
    }

    // projection: lane = (c,g); partial dot over j = 16g..16g+15, reduce over g
    const int c = lane & 15, g = lane >> 4;
    float r = 0.f;
#pragma unroll
    for (int i = 0; i < 16; ++i) {
        int j = (g << 4) + i;
        float aj = __shfl(acc, j);
        r += aj * QT[j * 17 + c];
    }
    r += __shfl_xor(r, 16);
    r += __shfl_xor(r, 32);
    if (lane < 16) {
        int o = n * NC + c;
        if constexpr (LAYER == 0) {
            out[o] = K[KD + c] + r;
        } else if constexpr (LAYER == 1) {
            out[o] += r;
        } else {
            out[o] += r + s1n * K[KU1 + c] + s2n * K[KU2 + c];
        }
    }
}

// h4 = b3 + agg(t4); out[n, :] += h4 * conv_w[:, 192]   (thread per node)
__global__ __launch_bounds__(256) void k_agg4_out(
    const float* __restrict__ t4, const int2* __restrict__ edges,
    const int* __restrict__ row_ptr, const float* __restrict__ b3,
    const float* __restrict__ conv_w, float* __restrict__ out) {
    int n = blockIdx.x * blockDim.x + threadIdx.x;
    if (n >= N) return;
    int p0 = row_ptr[n], p1 = row_ptr[n + 1];
    float a0 = 0.f, a1 = 0.f;
    for (int p = p0; p < p1; p += 4) {
        int2 e0 = edges[p + 0], e1 = edges[p + 1], e2 = edges[p + 2], e3 = edges[p + 3];
        float w0 = __int_as_float(e0.y);
        float w1 = (p + 1 < p1) ? __int_as_float(e1.y) : 0.f;
        float w2 = (p + 2 < p1) ? __int_as_float(e2.y) : 0.f;
        float w3 = (p + 3 < p1) ? __int_as_float(e3.y) : 0.f;
        a0 += w0 * t4[e0.x]; a1 += w1 * t4[e1.x];
        a0 += w2 * t4[e2.x]; a1 += w3 * t4[e3.x];
    }
    float h4 = a0 + a1 + b3[0];
    float4* o4 = (float4*)(out + n * NC);
#pragma unroll
    for (int k = 0; k < 4; ++k) {
        float4 v = o4[k];
        v.x += h4 * conv_w[(4 * k + 0) * TOT + 192];
        v.y += h4 * conv_w[(4 * k + 1) * TOT + 192];
        v.z += h4 * conv_w[(4 * k + 2) * TOT + 192];
        v.w += h4 * conv_w[(4 * k + 3) * TOT + 192];
        o4[k] = v;
    }
}

// ---------------- launch ----------------

extern "C" void kernel_launch(void* const* d_in, const int* in_sizes, int n_in,
                              void* d_out, int out_size, void* d_ws, size_t ws_size,
                              hipStream_t stream) {
    const float* x   = (const float*)d_in[0];
    const int*   ei  = (const int*)d_in[1];
    const int*   src = ei;
    const int*   dst = ei + E;
    const float* W0  = (const float*)d_in[3];
    const float* b0  = (const float*)d_in[4];
    const float* W1  = (const float*)d_in[5];
    const float* b1  = (const float*)d_in[6];
    const float* W2  = (const float*)d_in[7];
    const float* b2  = (const float*)d_in[8];
    const float* W3  = (const float*)d_in[9];
    const float* b3  = (const float*)d_in[10];
    const float* cw  = (const float*)d_in[11];
    const float* cb  = (const float*)d_in[12];
    float* out = (float*)d_out;

    char* p = (char*)d_ws;
    auto alloc = [&](size_t nbytes) {
        char* r = p;
        p += (nbytes + 255) & ~(size_t)255;
        return (void*)r;
    };
    int*    deg     = (int*)alloc((size_t)N * 4);
    int*    fill    = (int*)alloc((size_t)N * 4);
    int*    row_ptr = (int*)alloc((size_t)(N + 1) * 4);
    float*  dinv    = (float*)alloc((size_t)N * 4);
    int*    part    = (int*)alloc((size_t)NB * 4);
    int2*   edges   = (int2*)alloc((size_t)(TE + 16) * 8);
    ushort* xb      = (ushort*)alloc((size_t)N * 64 * 2);
    ushort* M1      = (ushort*)alloc((size_t)N * 64 * 2);
    ushort* M2      = (ushort*)alloc((size_t)N * 64 * 2);
    float*  s1      = (float*)alloc((size_t)N * 4);
    float*  s2      = (float*)alloc((size_t)N * 4);
    float*  t4      = (float*)alloc((size_t)N * 4);
    float*  K       = (float*)alloc((size_t)KSZ * 4);

    // weight-product setup (independent of graph)
    k_setup<<<1, 256, 0, stream>>>(W0, b0, W1, b1, W2, b2, W3, b3, cw, cb, K);
    // x -> bf16 (independent of graph)
    k_xbf<<<(N * 64 / 4 + 255) / 256, 256, 0, stream>>>(x, xb);

    // graph preprocessing (hierarchical scan: part -> scanpart -> scatter)
    k_init    <<<(N + 255) / 256, 256, 0, stream>>>(deg, fill, edges);
    k_count   <<<(E + 255) / 256, 256, 0, stream>>>(dst, deg);
    k_part    <<<NB, 256, 0, stream>>>(deg, part);
    k_scanpart<<<1, 256, 0, stream>>>(part);
    k_scatter <<<NB, 256, 0, stream>>>(deg, part, row_ptr, dinv);
    k_fill    <<<(TE + 255) / 256, 256, 0, stream>>>(src, dst, row_ptr, fill, dinv, edges);

    const int layerGrid = (N + 3) / 4;   // one wave / node, 4 waves / block

    k_layer<0><<<layerGrid, 256, 0, stream>>>(
        xb, edges, row_ptr, K, nullptr, nullptr, M1, s1, nullptr, out);
    k_layer<1><<<layerGrid, 256, 0, stream>>>(
        M1, edges, row_ptr, K, s1, nullptr, M2, s2, nullptr, out);
    k_layer<2><<<layerGrid, 256, 0, stream>>>(
        M2, edges, row_ptr, K, s1, s2, nullptr, nullptr, t4, out);
    k_agg4_out<<<(N + 255) / 256, 256, 0, stream>>>(t4, edges, row_ptr, b3, cw, out);
}

// Round 9
// 209.279 us; speedup vs baseline: 3.1396x; 1.0707x over previous
//
#include <hip/hip_runtime.h>
#include <math.h>

// Problem constants (fixed by the reference)
static constexpr int N    = 50000;   // nodes
static constexpr int E    = 800000;  // edges
static constexpr int TE   = E + N;   // edges + self loops
static constexpr int NC   = 16;      // conv1d channels
static constexpr int TOT  = 193;     // concat dim
static constexpr int NB   = (N + 255) / 256;  // 196 scan blocks

// K-buffer layout (floats)
static constexpr int KQ1 = 0;      // Q1[64][16] = W0 . cw1^T
static constexpr int KQ2 = 1024;   // Q2[64][16] = (W0W1) . cw2^T
static constexpr int KQ3 = 2048;   // Q3[64][16] = (W0W1) . (W2 . cw3^T)
static constexpr int KV  = 3072;   // v[64] = (W0W1) . (W2 W3)
static constexpr int KU1 = 3136;   // u1[16] = (b0W1)cw2^T + (b1W2)cw3^T
static constexpr int KU2 = 3152;   // u2[16] = (b0W1W2)cw3^T
static constexpr int KD  = 3168;   // d[16]  = b0 cw1^T + b1 cw2^T + b2 cw3^T + cb
static constexpr int KSC = 3184;   // alpha=(b0W1W2)W3, beta=(b1W2)W3, gamma=b2.W3
static constexpr int KSZ = 3200;

__device__ __forceinline__ float bf2f(unsigned short u) {
    union { unsigned int i; float f; } v; v.i = ((unsigned int)u) << 16; return v.f;
}
__device__ __forceinline__ unsigned short f2bf(float f) {
    union { float f; unsigned int i; } v; v.f = f;
    unsigned int b = v.i + 0x7FFFu + ((v.i >> 16) & 1u);   // RNE
    return (unsigned short)(b >> 16);
}

// ---------------- graph preprocessing ----------------

__global__ void k_init(int* __restrict__ deg, int2* __restrict__ edges) {
    int i = blockIdx.x * blockDim.x + threadIdx.x;
    if (i < N) deg[i] = 1;                        // self-loop reserves slot 0
    if (i < 32) edges[TE + i] = make_int2(0, 0);  // pad for unroll-16 overrun
}

// pos[e] = slot of edge e within its dst row (atomicAdd returns old count >= 1)
__global__ void k_count(const int* __restrict__ dst, int* __restrict__ deg,
                        int* __restrict__ pos) {
    int e = blockIdx.x * blockDim.x + threadIdx.x;
    if (e < E) pos[e] = atomicAdd(&deg[dst[e]], 1);
}

__global__ __launch_bounds__(256) void k_part(const int* __restrict__ deg,
                                              int* __restrict__ part) {
    __shared__ int red[256];
    const int t = threadIdx.x;
    int i = blockIdx.x * 256 + t;
    int v = (i < N) ? deg[i] : 0;
    red[t] = v;
    __syncthreads();
#pragma unroll
    for (int off = 128; off; off >>= 1) {
        if (t < off) red[t] += red[t + off];
        __syncthreads();
    }
    if (t == 0) part[blockIdx.x] = red[0];
}

__global__ __launch_bounds__(256) void k_scanpart(int* __restrict__ part) {
    __shared__ int s[256];
    const int t = threadIdx.x;
    int v = (t < NB) ? part[t] : 0;
    s[t] = v;
    __syncthreads();
#pragma unroll
    for (int off = 1; off < 256; off <<= 1) {
        int u = (t >= off) ? s[t - off] : 0;
        __syncthreads();
        s[t] += u;
        __syncthreads();
    }
    if (t < NB) part[t] = s[t] - v;  // exclusive prefix
}

__global__ __launch_bounds__(256) void k_scatter(const int* __restrict__ deg,
                                                 const int* __restrict__ part,
                                                 int* __restrict__ row_ptr,
                                                 float* __restrict__ dinv) {
    __shared__ int s[256];
    const int t = threadIdx.x;
    int i = blockIdx.x * 256 + t;
    int v = (i < N) ? deg[i] : 0;
    s[t] = v;
    __syncthreads();
#pragma unroll
    for (int off = 1; off < 256; off <<= 1) {
        int u = (t >= off) ? s[t - off] : 0;
        __syncthreads();
        s[t] += u;
        __syncthreads();
    }
    if (i < N) {
        int base = part[blockIdx.x];
        row_ptr[i] = base + s[t] - v;
        dinv[i] = rsqrtf((float)v);           // deg >= 1 always (self loop)
        if (i == N - 1) row_ptr[N] = base + s[t];
    }
}

// scatter edges into CSR; NO atomic (slot precomputed in pos[])
__global__ void k_fill(const int* __restrict__ src, const int* __restrict__ dst,
                       const int* __restrict__ pos,
                       const int* __restrict__ row_ptr,
                       const float* __restrict__ dinv,
                       int2* __restrict__ edges) {
    int idx = blockIdx.x * blockDim.x + threadIdx.x;
    if (idx < E) {
        int s = src[idx], d = dst[idx];
        int p = row_ptr[d] + pos[idx];
        edges[p] = make_int2(s, __float_as_int(dinv[s] * dinv[d]));
    } else if (idx < TE) {
        int i = idx - E;
        float dv = dinv[i];
        edges[row_ptr[i]] = make_int2(i, __float_as_int(dv * dv));  // slot 0
    }
}

// x (fp32) -> xb (bf16), vectorized: 4 floats / thread
__global__ __launch_bounds__(256) void k_xbf(const float* __restrict__ x,
                                             ushort* __restrict__ xb) {
    int i = blockIdx.x * 256 + threadIdx.x;
    if (i * 4 >= N * 64) return;
    float4 v = ((const float4*)x)[i];
    ushort4 o;
    o.x = f2bf(v.x); o.y = f2bf(v.y); o.z = f2bf(v.z); o.w = f2bf(v.w);
    ((ushort4*)xb)[i] = o;
}

// ---------------- setup: precompute combined weight products ----------------
__global__ __launch_bounds__(256) void k_setup(
    const float* __restrict__ W0, const float* __restrict__ b0,
    const float* __restrict__ W1, const float* __restrict__ b1,
    const float* __restrict__ W2, const float* __restrict__ b2,
    const float* __restrict__ W3, const float* __restrict__ b3,
    const float* __restrict__ cw, const float* __restrict__ cb,
    float* __restrict__ K) {
    __shared__ float W0s[4096], W1s[4096], W2s[4096], P2s[4096];
    __shared__ float C1[1024], C2[1024], C3[1024], R3s[1024];
    __shared__ float W3s[64], b0s[64], b1s[64], b2s[64];
    __shared__ float r3[64], rb1[64], rb2[64], rb12[64];
    const int t = threadIdx.x;
    const int k = t >> 2, q = t & 3;

    for (int i = t; i < 4096; i += 256) {
        W0s[i] = W0[i]; W1s[i] = W1[i]; W2s[i] = W2[i];
    }
    for (int i = t; i < 1024; i += 256) {
        int j = i >> 4, c = i & 15;       // C[j][c] = cw[c, off + j]
        C1[i] = cw[c * TOT + j];
        C2[i] = cw[c * TOT + 64 + j];
        C3[i] = cw[c * TOT + 128 + j];
    }
    if (t < 64) { W3s[t] = W3[t]; b0s[t] = b0[t]; b1s[t] = b1[t]; b2s[t] = b2[t]; }
    __syncthreads();

    // phase 1: P2 = W0 W1 ; R3 = W2 C3 ; r3 = W2 W3 ; rb1 = b0 W1 ; rb2 = b1 W2
    {
        const int j0 = q * 16;
        float acc[16];
#pragma unroll
        for (int jj = 0; jj < 16; ++jj) acc[jj] = 0.f;
        for (int m = 0; m < 64; ++m) {
            float w = W0s[k * 64 + m];
#pragma unroll
            for (int jj = 0; jj < 16; ++jj) acc[jj] += w * W1s[m * 64 + j0 + jj];
        }
#pragma unroll
        for (int jj = 0; jj < 16; ++jj) P2s[k * 64 + j0 + jj] = acc[jj];
    }
    {
        const int c0 = q * 4;
        float acc[4] = {0.f, 0.f, 0.f, 0.f};
        for (int j = 0; j < 64; ++j) {
            float w = W2s[k * 64 + j];
#pragma unroll
            for (int cc = 0; cc < 4; ++cc) acc[cc] += w * C3[j * 16 + c0 + cc];
        }
#pragma unroll
        for (int cc = 0; cc < 4; ++cc) R3s[k * 16 + c0 + cc] = acc[cc];
    }
    if (q == 0) {
        float a = 0.f;
        for (int j = 0; j < 64; ++j) a += W2s[k * 64 + j] * W3s[j];
        r3[k] = a;
    }
    if (q == 1) {
        float a = 0.f;
        for (int m = 0; m < 64; ++m) a += b0s[m] * W1s[m * 64 + k];
        rb1[k] = a;
    }
    if (q == 2) {
        float a = 0.f;
        for (int m = 0; m < 64; ++m) a += b1s[m] * W2s[m * 64 + k];
        rb2[k] = a;
    }
    __syncthreads();

    // phase 2: Q1 = W0 C1 ; Q2 = P2 C2 ; Q3 = P2 R3 ; v = P2 r3 ; rb12 = rb1 W2
    {
        const int c0 = q * 4;
        float q1[4] = {0,0,0,0}, q2[4] = {0,0,0,0}, q3[4] = {0,0,0,0};
        for (int j = 0; j < 64; ++j) {
            float w0 = W0s[k * 64 + j], p2 = P2s[k * 64 + j];
#pragma unroll
            for (int cc = 0; cc < 4; ++cc) {
                q1[cc] += w0 * C1[j * 16 + c0 + cc];
                q2[cc] += p2 * C2[j * 16 + c0 + cc];
                q3[cc] += p2 * R3s[j * 16 + c0 + cc];
            }
        }
#pragma unroll
        for (int cc = 0; cc < 4; ++cc) {
            K[KQ1 + k * 16 + c0 + cc] = q1[cc];
            K[KQ2 + k * 16 + c0 + cc] = q2[cc];
            K[KQ3 + k * 16 + c0 + cc] = q3[cc];
        }
    }
    if (q == 3) {
        float a = 0.f;
        for (int j = 0; j < 64; ++j) a += P2s[k * 64 + j] * r3[j];
        K[KV + k] = a;
    }
    if (q == 0) {
        float a = 0.f;
        for (int m = 0; m < 64; ++m) a += rb1[m] * W2s[m * 64 + k];
        rb12[k] = a;
    }
    __syncthreads();

    // phase 3: bias projections
    if (t < 16) {
        float a1 = 0.f, a2 = 0.f, ad = 0.f;
        for (int j = 0; j < 64; ++j) {
            a1 += rb1[j] * C2[j * 16 + t] + rb2[j] * C3[j * 16 + t];
            a2 += rb12[j] * C3[j * 16 + t];
            ad += b0s[j] * C1[j * 16 + t] + b1s[j] * C2[j * 16 + t]
                + b2s[j] * C3[j * 16 + t];
        }
        K[KU1 + t] = a1; K[KU2 + t] = a2; K[KD + t] = ad + cb[t];
    }
    if (t == 0) {
        float al = 0.f, be = 0.f, ga = 0.f;
        for (int j = 0; j < 64; ++j) {
            al += rb12[j] * W3s[j]; be += rb2[j] * W3s[j]; ga += b2s[j] * W3s[j];
        }
        K[KSC + 0] = al; K[KSC + 1] = be; K[KSC + 2] = ga;
    }
}

// ---------------- fused layer (M-basis, bf16 tables, unroll-16 gather) -----
// LAYER 0: M1 = S xb      ; s1[n] = row-sum(S) ; out  = d + M1.Q1
// LAYER 1: M2 = S M1      ; s2 = S s1          ; out += M2.Q2
// LAYER 2: (M3 = S M2 regs only) ; t4 = M3.v + a*s2 + b*s1 + g ;
//          out += M3.Q3 + s1*u1 + s2*u2
template <int LAYER>
__global__ __launch_bounds__(256) void k_layer(
    const ushort* __restrict__ Min,      // bf16 rows [*,64]
    const int2* __restrict__ edges,
    const int* __restrict__ row_ptr,
    const float* __restrict__ K,
    const float* __restrict__ s1in,
    const float* __restrict__ s2in,
    ushort* __restrict__ Mout,           // bf16 rows [*,64]
    float* __restrict__ s_out,
    float* __restrict__ t4,
    float* __restrict__ out) {
    __shared__ float QT[64 * 17];   // Q_LAYER, padded stride 17 (2-way banks max)
    const int tid = threadIdx.x;
    constexpr int KQ = (LAYER == 0) ? KQ1 : (LAYER == 1) ? KQ2 : KQ3;
    for (int i = tid; i < 1024; i += 256) {
        int j = i >> 4, c = i & 15;
        QT[j * 17 + c] = K[KQ + i];
    }
    const int lane = tid & 63;
    const int w = tid >> 6;
    float vv = 0.f;
    if constexpr (LAYER == 2) vv = K[KV + lane];
    __syncthreads();

    const int n = blockIdx.x * 4 + w;
    if (n >= N) return;

    const int p0 = __builtin_amdgcn_readfirstlane(row_ptr[n]);
    const int p1 = __builtin_amdgcn_readfirstlane(row_ptr[n + 1]);

    float acc0 = 0.f, acc1 = 0.f, accs = 0.f;
    for (int p = p0; p < p1; p += 16) {
        int2 e[16];
#pragma unroll
        for (int i = 0; i < 16; ++i) e[i] = edges[p + i];   // uniform -> s_load
        ushort g[16];
#pragma unroll
        for (int i = 0; i < 16; ++i) g[i] = Min[e[i].x * 64 + lane];
        float wv[16];
#pragma unroll
        for (int i = 0; i < 16; ++i)
            wv[i] = (i == 0 || p + i < p1) ? __int_as_float(e[i].y) : 0.f;
        if constexpr (LAYER == 0) {
#pragma unroll
            for (int i = 0; i < 16; ++i) accs += wv[i];
        }
#pragma unroll
        for (int i = 0; i < 16; i += 2) {
            acc0 += wv[i] * bf2f(g[i]);
            acc1 += wv[i + 1] * bf2f(g[i + 1]);
        }
    }
    const float acc = acc0 + acc1;

    if constexpr (LAYER < 2) Mout[n * 64 + lane] = f2bf(acc);
    if constexpr (LAYER == 0) {
        if (lane == 0) s_out[n] = accs;   // accs uniform across lanes
    }
    if constexpr (LAYER == 1) {
        // s2[n] = sum_p wgt * s1[col]   (edges spread across lanes)
        float ss = 0.f;
        for (int p = p0 + lane; p < p1; p += 64) {
            int2 e = edges[p];
            ss += __int_as_float(e.y) * s1in[e.x];
        }
#pragma unroll
        for (int off = 32; off; off >>= 1) ss += __shfl_xor(ss, off);
        if (lane == 0) s_out[n] = ss;
    }

    float s1n = 0.f, s2n = 0.f;
    if constexpr (LAYER == 2) {
        s1n = s1in[n]; s2n = s2in[n];
        float tv = acc * vv;
#pragma unroll
        for (int off = 32; off; off >>= 1) tv += __shfl_xor(tv, off);
        if (lane == 0)
            t4[n] = tv + K[KSC + 0] * s2n + K[KSC + 1] * s1n + K[KSC + 2];
    }

    // projection: lane = (c,g); partial dot over j = 16g..16g+15, reduce over g
    const int c = lane & 15, g = lane >> 4;
    float r = 0.f;
#pragma unroll
    for (int i = 0; i < 16; ++i) {
        int j = (g << 4) + i;
        float aj = __shfl(acc, j);
        r += aj * QT[j * 17 + c];
    }
    r += __shfl_xor(r, 16);
    r += __shfl_xor(r, 32);
    if (lane < 16) {
        int o = n * NC + c;
        if constexpr (LAYER == 0) {
            out[o] = K[KD + c] + r;
        } else if constexpr (LAYER == 1) {
            out[o] += r;
        } else {
            out[o] += r + s1n * K[KU1 + c] + s2n * K[KU2 + c];
        }
    }
}

// h4 = b3 + agg(t4); out[n, :] += h4 * conv_w[:, 192]   (thread per node)
__global__ __launch_bounds__(256) void k_agg4_out(
    const float* __restrict__ t4, const int2* __restrict__ edges,
    const int* __restrict__ row_ptr, const float* __restrict__ b3,
    const float* __restrict__ conv_w, float* __restrict__ out) {
    int n = blockIdx.x * blockDim.x + threadIdx.x;
    if (n >= N) return;
    int p0 = row_ptr[n], p1 = row_ptr[n + 1];
    float a0 = 0.f, a1 = 0.f;
    for (int p = p0; p < p1; p += 4) {
        int2 e0 = edges[p + 0], e1 = edges[p + 1], e2 = edges[p + 2], e3 = edges[p + 3];
        float w0 = __int_as_float(e0.y);
        float w1 = (p + 1 < p1) ? __int_as_float(e1.y) : 0.f;
        float w2 = (p + 2 < p1) ? __int_as_float(e2.y) : 0.f;
        float w3 = (p + 3 < p1) ? __int_as_float(e3.y) : 0.f;
        a0 += w0 * t4[e0.x]; a1 += w1 * t4[e1.x];
        a0 += w2 * t4[e2.x]; a1 += w3 * t4[e3.x];
    }
    float h4 = a0 + a1 + b3[0];
    float4* o4 = (float4*)(out + n * NC);
#pragma unroll
    for (int k = 0; k < 4; ++k) {
        float4 v = o4[k];
        v.x += h4 * conv_w[(4 * k + 0) * TOT + 192];
        v.y += h4 * conv_w[(4 * k + 1) * TOT + 192];
        v.z += h4 * conv_w[(4 * k + 2) * TOT + 192];
        v.w += h4 * conv_w[(4 * k + 3) * TOT + 192];
        o4[k] = v;
    }
}

// ---------------- launch ----------------

extern "C" void kernel_launch(void* const* d_in, const int* in_sizes, int n_in,
                              void* d_out, int out_size, void* d_ws, size_t ws_size,
                              hipStream_t stream) {
    const float* x   = (const float*)d_in[0];
    const int*   ei  = (const int*)d_in[1];
    const int*   src = ei;
    const int*   dst = ei + E;
    const float* W0  = (const float*)d_in[3];
    const float* b0  = (const float*)d_in[4];
    const float* W1  = (const float*)d_in[5];
    const float* b1  = (const float*)d_in[6];
    const float* W2  = (const float*)d_in[7];
    const float* b2  = (const float*)d_in[8];
    const float* W3  = (const float*)d_in[9];
    const float* b3  = (const float*)d_in[10];
    const float* cw  = (const float*)d_in[11];
    const float* cb  = (const float*)d_in[12];
    float* out = (float*)d_out;

    char* p = (char*)d_ws;
    auto alloc = [&](size_t nbytes) {
        char* r = p;
        p += (nbytes + 255) & ~(size_t)255;
        return (void*)r;
    };
    int*    deg     = (int*)alloc((size_t)N * 4);
    int*    pos     = (int*)alloc((size_t)E * 4);
    int*    row_ptr = (int*)alloc((size_t)(N + 1) * 4);
    float*  dinv    = (float*)alloc((size_t)N * 4);
    int*    part    = (int*)alloc((size_t)NB * 4);
    int2*   edges   = (int2*)alloc((size_t)(TE + 32) * 8);
    ushort* xb      = (ushort*)alloc((size_t)N * 64 * 2);
    ushort* M1      = (ushort*)alloc((size_t)N * 64 * 2);
    ushort* M2      = (ushort*)alloc((size_t)N * 64 * 2);
    float*  s1      = (float*)alloc((size_t)N * 4);
    float*  s2      = (float*)alloc((size_t)N * 4);
    float*  t4      = (float*)alloc((size_t)N * 4);
    float*  K       = (float*)alloc((size_t)KSZ * 4);

    // weight-product setup + x->bf16 (independent of graph)
    k_setup<<<1, 256, 0, stream>>>(W0, b0, W1, b1, W2, b2, W3, b3, cw, cb, K);
    k_xbf<<<(N * 64 / 4 + 255) / 256, 256, 0, stream>>>(x, xb);

    // graph preprocessing
    k_init    <<<(N + 255) / 256, 256, 0, stream>>>(deg, edges);
    k_count   <<<(E + 255) / 256, 256, 0, stream>>>(dst, deg, pos);
    k_part    <<<NB, 256, 0, stream>>>(deg, part);
    k_scanpart<<<1, 256, 0, stream>>>(part);
    k_scatter <<<NB, 256, 0, stream>>>(deg, part, row_ptr, dinv);
    k_fill    <<<(TE + 255) / 256, 256, 0, stream>>>(src, dst, pos, row_ptr, dinv, edges);

    const int layerGrid = (N + 3) / 4;   // one wave / node, 4 waves / block

    k_layer<0><<<layerGrid, 256, 0, stream>>>(
        xb, edges, row_ptr, K, nullptr, nullptr, M1, s1, nullptr, out);
    k_layer<1><<<layerGrid, 256, 0, stream>>>(
        M1, edges, row_ptr, K, s1, nullptr, M2, s2, nullptr, out);
    k_layer<2><<<layerGrid, 256, 0, stream>>>(
        M2, edges, row_ptr, K, s1, s2, nullptr, nullptr, t4, out);
    k_agg4_out<<<(N + 255) / 256, 256, 0, stream>>>(t4, edges, row_ptr, b3, cw, out);
}